// Round 1
// baseline (273.103 us; speedup 1.0000x reference)
//
#include <hip/hip_runtime.h>

#define NSEG 511
#define NROWS 8            // rows 8..15 only
#define ROW0 8
#define K0 21              // first needed freq bin
#define KEND 500           // bins k with 20 < k < 500
#define NFREQ 479
#define ACC_STRIDE 512     // padded per-row accumulator stride
#define ACC_ELEMS (2 * NROWS * ACC_STRIDE)   // one replica
#define NREP 8             // accumulator replicas
#define SPB 4              // segments per block
#define NGROUPS 128        // ceil(511/4)
#define NBLOCKS (2 * NROWS * NGROUPS)

// XOR swizzle for the FFT buffer (keeps quads contiguous).
__device__ __forceinline__ int sw(int i) { return i ^ (((i >> 5) & 7) << 2); }
// Base-8 digit reversal: inverse of the stage-D output map m(n)=64(n&7)+8((n>>3)&7)+(n>>6).
__device__ __forceinline__ int revq(int m) { return 64 * (m & 7) + 8 * ((m >> 3) & 7) + (m >> 6); }

__device__ __forceinline__ float2 cmul(float2 a, float2 b) {
    return make_float2(fmaf(a.x, b.x, -a.y * b.y), fmaf(a.x, b.y, a.y * b.x));
}
__device__ __forceinline__ float2 cadd(float2 a, float2 b) { return make_float2(a.x + b.x, a.y + b.y); }
__device__ __forceinline__ float2 csub(float2 a, float2 b) { return make_float2(a.x - b.x, a.y - b.y); }

// In-register 8-point DFT (DIF).
__device__ __forceinline__ void dft8(float2& x0, float2& x1, float2& x2, float2& x3,
                                     float2& x4, float2& x5, float2& x6, float2& x7) {
    const float C45 = 0.70710678118654752440f;
    float2 t0 = cadd(x0, x4), u0 = csub(x0, x4);
    float2 t1 = cadd(x1, x5), u1 = csub(x1, x5);
    float2 t2 = cadd(x2, x6), u2 = csub(x2, x6);
    float2 t3 = cadd(x3, x7), u3 = csub(x3, x7);
    float2 s0 = cadd(t0, t2), d0 = csub(t0, t2);
    float2 s1 = cadd(t1, t3), d1 = csub(t1, t3);
    float2 v1 = make_float2(C45 * (u1.x + u1.y), C45 * (u1.y - u1.x));
    float2 v2 = make_float2(u2.y, -u2.x);
    float2 v3 = make_float2(C45 * (u3.y - u3.x), -C45 * (u3.x + u3.y));
    float2 s2 = cadd(u0, v2), d2 = csub(u0, v2);
    float2 s3 = cadd(v1, v3), d3 = csub(v1, v3);
    float2 mid1 = make_float2(d1.y, -d1.x);   // -i * d1
    float2 mid3 = make_float2(d3.y, -d3.x);   // -i * d3
    x0 = cadd(s0, s1); x4 = csub(s0, s1);
    x2 = cadd(d0, mid1); x6 = csub(d0, mid1);
    x1 = cadd(s2, s3); x5 = csub(s2, s3);
    x3 = cadd(d2, mid3); x7 = csub(d2, mid3);
}

// x[p] *= W^p with W = (c, s) given.
__device__ __forceinline__ void twiddle8cs(float2& x1, float2& x2, float2& x3, float2& x4,
                                           float2& x5, float2& x6, float2& x7,
                                           float c, float s) {
    float2 w1 = make_float2(c, s);
    float2 w2 = cmul(w1, w1);
    float2 w3 = cmul(w2, w1);
    float2 w4 = cmul(w2, w2);
    float2 w5 = cmul(w4, w1);
    float2 w6 = cmul(w3, w3);
    float2 w7 = cmul(w4, w3);
    x1 = cmul(x1, w1); x2 = cmul(x2, w2); x3 = cmul(x3, w3);
    x4 = cmul(x4, w4); x5 = cmul(x5, w5); x6 = cmul(x6, w6);
    x7 = cmul(x7, w7);
}

// One block = one (signal, row, 4 consecutive segments). Per segment: windowed
// 4096-pt real FFT via register 2048-pt complex FFT (radices [8,8,8,4-fused]).
// Power accumulated in registers across segments; ONE atomic flush per thread.
// Barrier schedule (3 per segment, was 5):
//   A writes -> sync (A->B crosses waves)
//   B (intra-wave vs A-written data? no: B reads cross-wave data, covered by the
//     sync above; B's own read-modify-write is per-thread)
//   C        (B->C data flow is INTRA-WAVE: 32-block t>>5 is written by the same
//     32 threads that read it -> no barrier; wave lockstep + lgkmcnt order it)
//   sync (C -> untangle crosses waves)
//   untangle reads quads directly from buf (nat buffer eliminated)
//   sync (buf reuse by next segment's stage A; skipped on last segment)
__global__ __launch_bounds__(256, 6)
void psd_kernel(const float* __restrict__ pred,
                const float* __restrict__ target,
                float* __restrict__ acc) {
    __shared__ float2 buf[2048];   // 16 KiB FFT workspace (nat eliminated)

    const int bid = blockIdx.x;
    const int grp = bid % NGROUPS;
    const int row = (bid / NGROUPS) % NROWS + ROW0;
    const int sig = bid / (NGROUPS * NROWS);   // 0 = res (target-pred), 1 = target
    const int tid = threadIdx.x;
    const int seg0 = grp * SPB;
    const int ns = (seg0 + SPB <= NSEG) ? SPB : (NSEG - seg0);   // 4 (last group: 3)
    float* accR = acc + (bid & (NREP - 1)) * ACC_ELEMS;

    const float2* t2p = (const float2*)target;
    const float2* p2p = (const float2*)pred;

    // Complex point m of segment s: real samples at batch row 2(seg0+s)+(m>>9),
    // float2 offset row*512 + (m&511). m = tid + 256*R.
    const int base = 2 * seg0 * 8192 + row * 512 + tid;
#define LOADRAW(X, IDX)                                                      \
    {                                                                        \
        int _i = (IDX);                                                      \
        float2 v = t2p[_i];                                                  \
        if (sig == 0) { float2 p = p2p[_i]; v.x -= p.x; v.y -= p.y; }        \
        X = v;                                                               \
    }
    float2 r0, r1, r2, r3, r4, r5, r6, r7;
    LOADRAW(r0, base)
    LOADRAW(r1, base + 256)
    LOADRAW(r2, base + 8192)
    LOADRAW(r3, base + 8448)
    LOADRAW(r4, base + 16384)
    LOADRAW(r5, base + 16640)
    LOADRAW(r6, base + 24576)
    LOADRAW(r7, base + 24832)

    // ---- hoisted trig (segment-invariant) ----
    const float WA = 3.06796157577128245e-3f;      // 2*pi/2048
    const float CD = 0.99999882344642529f;         // cos(pi/2048)
    const float SD = 1.53398018628476550e-3f;      // sin(pi/2048)
    const float H  = 0.70710678118654752440f;      // sqrt(2)/2
    float sa, ca;
    __sincosf((float)tid * WA, &sa, &ca);          // window base; stage-A tw = (ca,-sa)
    // stage-B twiddle base (depends on tid&31 only)
    float sb, cb;
    __sincosf((float)(tid & 31) * -2.45436926061702596e-2f, &sb, &cb);  // -2*pi/256
    // stage-C twiddle base (depends on tid&3 only): constants
    float cc, ss;
    {
        const float TC1 = 0.98078528040323044913f, TS1 = -0.19509032201612826785f;
        const float TC2 = 0.92387953251128675613f, TS2 = -0.38268343236508977173f;
        const float TC3 = 0.83146961230254523708f, TS3 = -0.55557023301960222474f;
        int mq = tid & 3;
        cc = (mq & 2) ? ((mq & 1) ? TC3 : TC2) : ((mq & 1) ? TC1 : 1.0f);
        ss = (mq & 2) ? ((mq & 1) ? TS3 : TS2) : ((mq & 1) ? TS1 : 0.0f);
    }
    // untangle twiddles for bins k1 = K0+tid and k2 = k1+256 (-pi/8 rotation)
    float sn0, cs0, sn1, cs1;
    __sincosf(-1.53398078788564123e-3f * (float)(K0 + tid), &sn0, &cs0);  // -2*pi*k/4096
    {
        const float CU = 0.98078528040323044913f;   // cos(pi/8)
        const float SU = 0.19509032201612826785f;   // sin(pi/8)
        cs1 = cs0 * CU + sn0 * SU;
        sn1 = sn0 * CU - cs0 * SU;
    }
    // Untangle quad addresses (segment-invariant, float4 index into buf):
    // bin k needs X0 of quad m=k (Z[k]) and X3 of quad m=512-k (Z[2048-k]).
    const int qA1 = sw(4 * revq(K0 + tid)) >> 1;
    const int qB1 = sw(4 * revq(512 - (K0 + tid))) >> 1;
    int qA2 = 0, qB2 = 0;
    if (tid < KEND - K0 - 256) {
        qA2 = sw(4 * revq(K0 + 256 + tid)) >> 1;
        qB2 = sw(4 * revq(512 - (K0 + 256 + tid))) >> 1;
    }

    float pw1 = 0.0f, pw2 = 0.0f;   // register power accumulators (2 bins/thread)
    float4* b4 = (float4*)buf;

    #pragma unroll 1
    for (int s = 0; s < ns; ++s) {
        // ---- window coefficients: recomputed per segment (frees 16 persistent
        // VGPRs; asm touch defeats LICM so they stay transient)
        float cat = ca, sat = sa;
        asm volatile("" : "+v"(cat), "+v"(sat));
        float2 wv0, wv1, wv2, wv3, wv4, wv5, wv6, wv7;
#define MKW(W, CE, SE) { float cr = (CE), sr = (SE);                         \
        W = make_float2(1.0f - cr, 1.0f - (cr * CD - sr * SD)); }
        MKW(wv0, cat, sat)
        MKW(wv1, H * (cat - sat), H * (sat + cat))
        MKW(wv2, -sat, cat)
        MKW(wv3, -H * (cat + sat), H * (cat - sat))
        MKW(wv4, -cat, -sat)
        MKW(wv5, H * (sat - cat), -H * (sat + cat))
        MKW(wv6, sat, -cat)
        MKW(wv7, H * (cat + sat), H * (sat - cat))
#undef MKW

        // ---- window raw -> x
        float2 x0 = make_float2(r0.x * wv0.x, r0.y * wv0.y);
        float2 x1 = make_float2(r1.x * wv1.x, r1.y * wv1.y);
        float2 x2 = make_float2(r2.x * wv2.x, r2.y * wv2.y);
        float2 x3 = make_float2(r3.x * wv3.x, r3.y * wv3.y);
        float2 x4 = make_float2(r4.x * wv4.x, r4.y * wv4.y);
        float2 x5 = make_float2(r5.x * wv5.x, r5.y * wv5.y);
        float2 x6 = make_float2(r6.x * wv6.x, r6.y * wv6.y);
        float2 x7 = make_float2(r7.x * wv7.x, r7.y * wv7.y);

        // ---- shift overlap half + prefetch next segment's new half (issued
        // now, consumed next iteration -> latency hidden under this FFT)
        if (s + 1 < ns) {
            r0 = r4; r1 = r5; r2 = r6; r3 = r7;
            int nb = base + (s + 1) * 16384;
            LOADRAW(r4, nb + 16384)
            LOADRAW(r5, nb + 16640)
            LOADRAW(r6, nb + 24576)
            LOADRAW(r7, nb + 24832)
        }

        // ---- stage A: radix-8 stride 256, twiddle W2048^{tid*p} = (ca,-sa)
        dft8(x0, x1, x2, x3, x4, x5, x6, x7);
        twiddle8cs(x1, x2, x3, x4, x5, x6, x7, ca, -sa);
        buf[sw(tid)]        = x0;
        buf[sw(tid + 256)]  = x1;
        buf[sw(tid + 512)]  = x2;
        buf[sw(tid + 768)]  = x3;
        buf[sw(tid + 1024)] = x4;
        buf[sw(tid + 1280)] = x5;
        buf[sw(tid + 1536)] = x6;
        buf[sw(tid + 1792)] = x7;
        __syncthreads();   // A->B crosses waves

        // ---- stage B: radix-8 stride 32 within each 256-subFFT
        {
            const int baseB = (tid & 31) + 256 * (tid >> 5);
            x0 = buf[sw(baseB)];
            x1 = buf[sw(baseB + 32)];
            x2 = buf[sw(baseB + 64)];
            x3 = buf[sw(baseB + 96)];
            x4 = buf[sw(baseB + 128)];
            x5 = buf[sw(baseB + 160)];
            x6 = buf[sw(baseB + 192)];
            x7 = buf[sw(baseB + 224)];
            dft8(x0, x1, x2, x3, x4, x5, x6, x7);
            twiddle8cs(x1, x2, x3, x4, x5, x6, x7, cb, sb);
            buf[sw(baseB)]       = x0;
            buf[sw(baseB + 32)]  = x1;
            buf[sw(baseB + 64)]  = x2;
            buf[sw(baseB + 96)]  = x3;
            buf[sw(baseB + 128)] = x4;
            buf[sw(baseB + 160)] = x5;
            buf[sw(baseB + 192)] = x6;
            buf[sw(baseB + 224)] = x7;
        }
        // NO barrier: B->C data flow is intra-wave (32-block t>>5 belongs to
        // wave t>>6 on both sides; lgkmcnt ordering suffices within a wave)

        // ---- stage C: radix-8 stride 4 within each 32-subFFT
        {
            const int baseC = (tid & 3) + 32 * ((tid >> 2) & 7) + 256 * (tid >> 5);
            x0 = buf[sw(baseC)];
            x1 = buf[sw(baseC + 4)];
            x2 = buf[sw(baseC + 8)];
            x3 = buf[sw(baseC + 12)];
            x4 = buf[sw(baseC + 16)];
            x5 = buf[sw(baseC + 20)];
            x6 = buf[sw(baseC + 24)];
            x7 = buf[sw(baseC + 28)];
            dft8(x0, x1, x2, x3, x4, x5, x6, x7);
            twiddle8cs(x1, x2, x3, x4, x5, x6, x7, cc, ss);
            buf[sw(baseC)]      = x0;
            buf[sw(baseC + 4)]  = x1;
            buf[sw(baseC + 8)]  = x2;
            buf[sw(baseC + 12)] = x3;
            buf[sw(baseC + 16)] = x4;
            buf[sw(baseC + 20)] = x5;
            buf[sw(baseC + 24)] = x6;
            buf[sw(baseC + 28)] = x7;
        }
        __syncthreads();   // C -> untangle crosses waves

        // ---- fused stage D + untangle: read the two quads for each bin
        // directly (quad n holds length-4 DFT inputs for bins 512v+m(n);
        // X0 = v=0 term = Z[m], X3 = v=3 term = Z[1536+m] = Z[2048-(512-m)]).
        {
            float4 lo = b4[qA1], hi = b4[qA1 + 1];
            float2 zk = make_float2((lo.x + hi.x) + (lo.z + hi.z),
                                    (lo.y + hi.y) + (lo.w + hi.w));
            lo = b4[qB1]; hi = b4[qB1 + 1];
            float D0x = lo.x - hi.x, D0y = lo.y - hi.y;
            float D1x = lo.z - hi.z, D1y = lo.w - hi.w;
            float2 zn = make_float2(D0x - D1y, D0y + D1x);
            float Ex = 0.5f * (zk.x + zn.x);
            float Ey = 0.5f * (zk.y - zn.y);
            float Ox = 0.5f * (zk.y + zn.y);
            float Oy = -0.5f * (zk.x - zn.x);
            float xr = Ex + Ox * cs0 - Oy * sn0;
            float xi = Ey + Ox * sn0 + Oy * cs0;
            pw1 += xr * xr + xi * xi;
        }
        if (tid < KEND - K0 - 256) {                // k2 = K0+256+tid < 500
            float4 lo = b4[qA2], hi = b4[qA2 + 1];
            float2 zk = make_float2((lo.x + hi.x) + (lo.z + hi.z),
                                    (lo.y + hi.y) + (lo.w + hi.w));
            lo = b4[qB2]; hi = b4[qB2 + 1];
            float D0x = lo.x - hi.x, D0y = lo.y - hi.y;
            float D1x = lo.z - hi.z, D1y = lo.w - hi.w;
            float2 zn = make_float2(D0x - D1y, D0y + D1x);
            float Ex = 0.5f * (zk.x + zn.x);
            float Ey = 0.5f * (zk.y - zn.y);
            float Ox = 0.5f * (zk.y + zn.y);
            float Oy = -0.5f * (zk.x - zn.x);
            float xr = Ex + Ox * cs1 - Oy * sn1;
            float xi = Ey + Ox * sn1 + Oy * cs1;
            pw2 += xr * xr + xi * xi;
        }
        if (s + 1 < ns) __syncthreads();   // buf reuse by next stage A
    }

    // ---- single atomic flush per thread (atomics cut 4x vs per-segment)
    {
        int i0 = (sig * NROWS + (row - ROW0)) * ACC_STRIDE;
        atomicAdd(&accR[i0 + tid], pw1);
        if (tid < KEND - K0 - 256) atomicAdd(&accR[i0 + 256 + tid], pw2);
    }
#undef LOADRAW
}

// Single block: out = sum over (row,k) of P_res/P_tgt, / 240.
// (dfreq=1, scale=480, mean(last 8)*16 => 2/480 = 1/240; /T cancels in ratio)
__global__ __launch_bounds__(256)
void reduce_kernel(const float* __restrict__ acc, float* __restrict__ out) {
    __shared__ float sh[256];
    int tid = threadIdx.x;
    float sum = 0.0f;
    for (int n = tid; n < NROWS * NFREQ; n += 256) {
        int r = n / NFREQ, k = n % NFREQ;
        float num = 0.0f, den = 0.0f;
        #pragma unroll
        for (int rep = 0; rep < NREP; ++rep) {
            num += acc[rep * ACC_ELEMS + r * ACC_STRIDE + k];
            den += acc[rep * ACC_ELEMS + (NROWS + r) * ACC_STRIDE + k];
        }
        sum += num / den;
    }
    sh[tid] = sum;
    __syncthreads();
    for (int s = 128; s > 0; s >>= 1) {
        if (tid < s) sh[tid] += sh[tid + s];
        __syncthreads();
    }
    if (tid == 0) out[0] = sh[0] * (1.0f / 240.0f);
}

extern "C" void kernel_launch(void* const* d_in, const int* in_sizes, int n_in,
                              void* d_out, int out_size, void* d_ws, size_t ws_size,
                              hipStream_t stream) {
    const float* pred = (const float*)d_in[0];
    const float* target = (const float*)d_in[1];
    float* acc = (float*)d_ws;   // NREP replicas of [2][NROWS][ACC_STRIDE] = 256 KiB

    hipMemsetAsync(acc, 0, NREP * ACC_ELEMS * sizeof(float), stream);
    psd_kernel<<<NBLOCKS, 256, 0, stream>>>(pred, target, acc);
    reduce_kernel<<<1, 256, 0, stream>>>(acc, (float*)d_out);
}

// Round 2
// 174.009 us; speedup vs baseline: 1.5695x; 1.5695x over previous
//
#include <hip/hip_runtime.h>

#define NSEG 511
#define NROWS 8            // rows 8..15 only
#define ROW0 8
#define K0 21              // first needed freq bin
#define KEND 500           // bins k with 20 < k < 500
#define NFREQ 479
#define ACC_STRIDE 512     // padded per-row accumulator stride
#define ACC_ELEMS (2 * NROWS * ACC_STRIDE)   // one replica
#define NREP 8             // accumulator replicas
#define SPB 4              // segments per block
#define NGROUPS 128        // ceil(511/4)
#define NBLOCKS (2 * NROWS * NGROUPS)

// XOR swizzle for the FFT buffer (keeps quads contiguous).
__device__ __forceinline__ int sw(int i) { return i ^ (((i >> 5) & 7) << 2); }
// Base-8 digit reversal: inverse of the stage-D output map m(n)=64(n&7)+8((n>>3)&7)+(n>>6).
__device__ __forceinline__ int revq(int m) { return 64 * (m & 7) + 8 * ((m >> 3) & 7) + (m >> 6); }

__device__ __forceinline__ float2 cmul(float2 a, float2 b) {
    return make_float2(fmaf(a.x, b.x, -a.y * b.y), fmaf(a.x, b.y, a.y * b.x));
}
__device__ __forceinline__ float2 cadd(float2 a, float2 b) { return make_float2(a.x + b.x, a.y + b.y); }
__device__ __forceinline__ float2 csub(float2 a, float2 b) { return make_float2(a.x - b.x, a.y - b.y); }

// In-register 8-point DFT (DIF).
__device__ __forceinline__ void dft8(float2& x0, float2& x1, float2& x2, float2& x3,
                                     float2& x4, float2& x5, float2& x6, float2& x7) {
    const float C45 = 0.70710678118654752440f;
    float2 t0 = cadd(x0, x4), u0 = csub(x0, x4);
    float2 t1 = cadd(x1, x5), u1 = csub(x1, x5);
    float2 t2 = cadd(x2, x6), u2 = csub(x2, x6);
    float2 t3 = cadd(x3, x7), u3 = csub(x3, x7);
    float2 s0 = cadd(t0, t2), d0 = csub(t0, t2);
    float2 s1 = cadd(t1, t3), d1 = csub(t1, t3);
    float2 v1 = make_float2(C45 * (u1.x + u1.y), C45 * (u1.y - u1.x));
    float2 v2 = make_float2(u2.y, -u2.x);
    float2 v3 = make_float2(C45 * (u3.y - u3.x), -C45 * (u3.x + u3.y));
    float2 s2 = cadd(u0, v2), d2 = csub(u0, v2);
    float2 s3 = cadd(v1, v3), d3 = csub(v1, v3);
    float2 mid1 = make_float2(d1.y, -d1.x);   // -i * d1
    float2 mid3 = make_float2(d3.y, -d3.x);   // -i * d3
    x0 = cadd(s0, s1); x4 = csub(s0, s1);
    x2 = cadd(d0, mid1); x6 = csub(d0, mid1);
    x1 = cadd(s2, s3); x5 = csub(s2, s3);
    x3 = cadd(d2, mid3); x7 = csub(d2, mid3);
}

// x[p] *= W^p with W = (c, s) given.
__device__ __forceinline__ void twiddle8cs(float2& x1, float2& x2, float2& x3, float2& x4,
                                           float2& x5, float2& x6, float2& x7,
                                           float c, float s) {
    float2 w1 = make_float2(c, s);
    float2 w2 = cmul(w1, w1);
    float2 w3 = cmul(w2, w1);
    float2 w4 = cmul(w2, w2);
    float2 w5 = cmul(w4, w1);
    float2 w6 = cmul(w3, w3);
    float2 w7 = cmul(w4, w3);
    x1 = cmul(x1, w1); x2 = cmul(x2, w2); x3 = cmul(x3, w3);
    x4 = cmul(x4, w4); x5 = cmul(x5, w5); x6 = cmul(x6, w6);
    x7 = cmul(x7, w7);
}

// One block = one (signal, row, 4 consecutive segments). Per segment: windowed
// 4096-pt real FFT via register 2048-pt complex FFT (radices [8,8,8,4-fused]).
// Power accumulated in registers across segments; ONE atomic flush per thread.
// Barrier schedule (3 per segment):
//   A -> sync -> B -> (no barrier, intra-wave) -> C -> sync -> untangle -> sync
// Untangle reads quads directly from buf (nat buffer eliminated). Thread->bin
// assignment permuted by sigma (swap low octal digits) so the digit-reversed
// quad addresses spread across banks (<=2-way, free) instead of 8..16-way.
// NOTE: __launch_bounds__(256) ONLY — forcing min-waves=6 made the allocator
// spill (VGPR 40, 165 MB scratch writes, 3x regression in round 1).
__global__ __launch_bounds__(256)
void psd_kernel(const float* __restrict__ pred,
                const float* __restrict__ target,
                float* __restrict__ acc) {
    __shared__ float2 buf[2048];   // 16 KiB FFT workspace (nat eliminated)

    const int bid = blockIdx.x;
    const int grp = bid % NGROUPS;
    const int row = (bid / NGROUPS) % NROWS + ROW0;
    const int sig = bid / (NGROUPS * NROWS);   // 0 = res (target-pred), 1 = target
    const int tid = threadIdx.x;
    const int seg0 = grp * SPB;
    const int ns = (seg0 + SPB <= NSEG) ? SPB : (NSEG - seg0);   // 4 (last group: 3)
    float* accR = acc + (bid & (NREP - 1)) * ACC_ELEMS;

    const float2* t2p = (const float2*)target;
    const float2* p2p = (const float2*)pred;

    // Complex point m of segment s: real samples at batch row 2(seg0+s)+(m>>9),
    // float2 offset row*512 + (m&511). m = tid + 256*R.
    const int base = 2 * seg0 * 8192 + row * 512 + tid;
#define LOADRAW(X, IDX)                                                      \
    {                                                                        \
        int _i = (IDX);                                                      \
        float2 v = t2p[_i];                                                  \
        if (sig == 0) { float2 p = p2p[_i]; v.x -= p.x; v.y -= p.y; }        \
        X = v;                                                               \
    }
    float2 r0, r1, r2, r3, r4, r5, r6, r7;
    LOADRAW(r0, base)
    LOADRAW(r1, base + 256)
    LOADRAW(r2, base + 8192)
    LOADRAW(r3, base + 8448)
    LOADRAW(r4, base + 16384)
    LOADRAW(r5, base + 16640)
    LOADRAW(r6, base + 24576)
    LOADRAW(r7, base + 24832)

    // ---- hoisted trig (segment-invariant) ----
    const float WA = 3.06796157577128245e-3f;      // 2*pi/2048
    const float CD = 0.99999882344642529f;         // cos(pi/2048)
    const float SD = 1.53398018628476550e-3f;      // sin(pi/2048)
    const float H  = 0.70710678118654752440f;      // sqrt(2)/2
    float sa, ca;
    __sincosf((float)tid * WA, &sa, &ca);          // window base; stage-A tw = (ca,-sa)
    // stage-B twiddle base (depends on tid&31 only)
    float sb, cb;
    __sincosf((float)(tid & 31) * -2.45436926061702596e-2f, &sb, &cb);  // -2*pi/256
    // stage-C twiddle base (depends on tid&3 only): constants
    float cc, ss;
    {
        const float TC1 = 0.98078528040323044913f, TS1 = -0.19509032201612826785f;
        const float TC2 = 0.92387953251128675613f, TS2 = -0.38268343236508977173f;
        const float TC3 = 0.83146961230254523708f, TS3 = -0.55557023301960222474f;
        int mq = tid & 3;
        cc = (mq & 2) ? ((mq & 1) ? TC3 : TC2) : ((mq & 1) ? TC1 : 1.0f);
        ss = (mq & 2) ? ((mq & 1) ? TS3 : TS2) : ((mq & 1) ? TS1 : 0.0f);
    }

    // ---- permuted thread->bin map: sigma swaps the two low octal digits so
    // consecutive lanes vary the MIDDLE digit of k, spreading the
    // digit-reversed quad addresses across LDS bank groups.
    const int sigma = (tid & 0xC0) | ((tid & 7) << 3) | ((tid >> 3) & 7);
    const int k1 = K0 + sigma;                 // 21..276, always < 500
    const bool has2 = (sigma < KEND - K0 - 256);   // k2 = k1+256 < 500

    // untangle twiddles for bins k1 and k2 = k1+256 (-pi/8 rotation)
    float sn0, cs0, sn1, cs1;
    __sincosf(-1.53398078788564123e-3f * (float)k1, &sn0, &cs0);  // -2*pi*k/4096
    {
        const float CU = 0.98078528040323044913f;   // cos(pi/8)
        const float SU = 0.19509032201612826785f;   // sin(pi/8)
        cs1 = cs0 * CU + sn0 * SU;
        sn1 = sn0 * CU - cs0 * SU;
    }
    // Untangle quad addresses (segment-invariant, float4 index into buf):
    // bin k needs X0 of quad m=k (Z[k]) and X3 of quad m=512-k (Z[2048-k]).
    const int qA1 = sw(4 * revq(k1)) >> 1;
    const int qB1 = sw(4 * revq(512 - k1)) >> 1;
    int qA2 = 0, qB2 = 0;
    if (has2) {
        qA2 = sw(4 * revq(k1 + 256)) >> 1;
        qB2 = sw(4 * revq(512 - (k1 + 256))) >> 1;
    }

    float pw1 = 0.0f, pw2 = 0.0f;   // register power accumulators (2 bins/thread)
    float4* b4 = (float4*)buf;

    #pragma unroll 1
    for (int s = 0; s < ns; ++s) {
        // ---- window coefficients: recomputed per segment (frees 16 persistent
        // VGPRs; asm touch defeats LICM so they stay transient)
        float cat = ca, sat = sa;
        asm volatile("" : "+v"(cat), "+v"(sat));
        float2 wv0, wv1, wv2, wv3, wv4, wv5, wv6, wv7;
#define MKW(W, CE, SE) { float cr = (CE), sr = (SE);                         \
        W = make_float2(1.0f - cr, 1.0f - (cr * CD - sr * SD)); }
        MKW(wv0, cat, sat)
        MKW(wv1, H * (cat - sat), H * (sat + cat))
        MKW(wv2, -sat, cat)
        MKW(wv3, -H * (cat + sat), H * (cat - sat))
        MKW(wv4, -cat, -sat)
        MKW(wv5, H * (sat - cat), -H * (sat + cat))
        MKW(wv6, sat, -cat)
        MKW(wv7, H * (cat + sat), H * (sat - cat))
#undef MKW

        // ---- window raw -> x
        float2 x0 = make_float2(r0.x * wv0.x, r0.y * wv0.y);
        float2 x1 = make_float2(r1.x * wv1.x, r1.y * wv1.y);
        float2 x2 = make_float2(r2.x * wv2.x, r2.y * wv2.y);
        float2 x3 = make_float2(r3.x * wv3.x, r3.y * wv3.y);
        float2 x4 = make_float2(r4.x * wv4.x, r4.y * wv4.y);
        float2 x5 = make_float2(r5.x * wv5.x, r5.y * wv5.y);
        float2 x6 = make_float2(r6.x * wv6.x, r6.y * wv6.y);
        float2 x7 = make_float2(r7.x * wv7.x, r7.y * wv7.y);

        // ---- shift overlap half + prefetch next segment's new half (issued
        // now, consumed next iteration -> latency hidden under this FFT)
        if (s + 1 < ns) {
            r0 = r4; r1 = r5; r2 = r6; r3 = r7;
            int nb = base + (s + 1) * 16384;
            LOADRAW(r4, nb + 16384)
            LOADRAW(r5, nb + 16640)
            LOADRAW(r6, nb + 24576)
            LOADRAW(r7, nb + 24832)
        }

        // ---- stage A: radix-8 stride 256, twiddle W2048^{tid*p} = (ca,-sa)
        dft8(x0, x1, x2, x3, x4, x5, x6, x7);
        twiddle8cs(x1, x2, x3, x4, x5, x6, x7, ca, -sa);
        buf[sw(tid)]        = x0;
        buf[sw(tid + 256)]  = x1;
        buf[sw(tid + 512)]  = x2;
        buf[sw(tid + 768)]  = x3;
        buf[sw(tid + 1024)] = x4;
        buf[sw(tid + 1280)] = x5;
        buf[sw(tid + 1536)] = x6;
        buf[sw(tid + 1792)] = x7;
        __syncthreads();   // A->B crosses waves

        // ---- stage B: radix-8 stride 32 within each 256-subFFT
        {
            const int baseB = (tid & 31) + 256 * (tid >> 5);
            x0 = buf[sw(baseB)];
            x1 = buf[sw(baseB + 32)];
            x2 = buf[sw(baseB + 64)];
            x3 = buf[sw(baseB + 96)];
            x4 = buf[sw(baseB + 128)];
            x5 = buf[sw(baseB + 160)];
            x6 = buf[sw(baseB + 192)];
            x7 = buf[sw(baseB + 224)];
            dft8(x0, x1, x2, x3, x4, x5, x6, x7);
            twiddle8cs(x1, x2, x3, x4, x5, x6, x7, cb, sb);
            buf[sw(baseB)]       = x0;
            buf[sw(baseB + 32)]  = x1;
            buf[sw(baseB + 64)]  = x2;
            buf[sw(baseB + 96)]  = x3;
            buf[sw(baseB + 128)] = x4;
            buf[sw(baseB + 160)] = x5;
            buf[sw(baseB + 192)] = x6;
            buf[sw(baseB + 224)] = x7;
        }
        // NO barrier: B->C data flow is intra-wave (32-block t>>5 belongs to
        // wave t>>6 on both sides; lgkmcnt ordering suffices within a wave)

        // ---- stage C: radix-8 stride 4 within each 32-subFFT
        {
            const int baseC = (tid & 3) + 32 * ((tid >> 2) & 7) + 256 * (tid >> 5);
            x0 = buf[sw(baseC)];
            x1 = buf[sw(baseC + 4)];
            x2 = buf[sw(baseC + 8)];
            x3 = buf[sw(baseC + 12)];
            x4 = buf[sw(baseC + 16)];
            x5 = buf[sw(baseC + 20)];
            x6 = buf[sw(baseC + 24)];
            x7 = buf[sw(baseC + 28)];
            dft8(x0, x1, x2, x3, x4, x5, x6, x7);
            twiddle8cs(x1, x2, x3, x4, x5, x6, x7, cc, ss);
            buf[sw(baseC)]      = x0;
            buf[sw(baseC + 4)]  = x1;
            buf[sw(baseC + 8)]  = x2;
            buf[sw(baseC + 12)] = x3;
            buf[sw(baseC + 16)] = x4;
            buf[sw(baseC + 20)] = x5;
            buf[sw(baseC + 24)] = x6;
            buf[sw(baseC + 28)] = x7;
        }
        __syncthreads();   // C -> untangle crosses waves

        // ---- fused stage D + untangle: read the two quads for each bin
        // directly (quad n holds length-4 DFT inputs for bins 512v+m(n);
        // X0 = v=0 term = Z[m], X3 = v=3 term = Z[1536+m] = Z[2048-(512-m)]).
        {
            float4 lo = b4[qA1], hi = b4[qA1 + 1];
            float2 zk = make_float2((lo.x + hi.x) + (lo.z + hi.z),
                                    (lo.y + hi.y) + (lo.w + hi.w));
            lo = b4[qB1]; hi = b4[qB1 + 1];
            float D0x = lo.x - hi.x, D0y = lo.y - hi.y;
            float D1x = lo.z - hi.z, D1y = lo.w - hi.w;
            float2 zn = make_float2(D0x - D1y, D0y + D1x);
            float Ex = 0.5f * (zk.x + zn.x);
            float Ey = 0.5f * (zk.y - zn.y);
            float Ox = 0.5f * (zk.y + zn.y);
            float Oy = -0.5f * (zk.x - zn.x);
            float xr = Ex + Ox * cs0 - Oy * sn0;
            float xi = Ey + Ox * sn0 + Oy * cs0;
            pw1 += xr * xr + xi * xi;
        }
        if (has2) {
            float4 lo = b4[qA2], hi = b4[qA2 + 1];
            float2 zk = make_float2((lo.x + hi.x) + (lo.z + hi.z),
                                    (lo.y + hi.y) + (lo.w + hi.w));
            lo = b4[qB2]; hi = b4[qB2 + 1];
            float D0x = lo.x - hi.x, D0y = lo.y - hi.y;
            float D1x = lo.z - hi.z, D1y = lo.w - hi.w;
            float2 zn = make_float2(D0x - D1y, D0y + D1x);
            float Ex = 0.5f * (zk.x + zn.x);
            float Ey = 0.5f * (zk.y - zn.y);
            float Ox = 0.5f * (zk.y + zn.y);
            float Oy = -0.5f * (zk.x - zn.x);
            float xr = Ex + Ox * cs1 - Oy * sn1;
            float xi = Ey + Ox * sn1 + Oy * cs1;
            pw2 += xr * xr + xi * xi;
        }
        if (s + 1 < ns) __syncthreads();   // buf reuse by next stage A
    }

    // ---- single atomic flush per thread (atomics cut 4x vs per-segment)
    {
        int i0 = (sig * NROWS + (row - ROW0)) * ACC_STRIDE;
        atomicAdd(&accR[i0 + sigma], pw1);
        if (has2) atomicAdd(&accR[i0 + 256 + sigma], pw2);
    }
#undef LOADRAW
}

// Single block: out = sum over (row,k) of P_res/P_tgt, / 240.
// (dfreq=1, scale=480, mean(last 8)*16 => 2/480 = 1/240; /T cancels in ratio)
__global__ __launch_bounds__(256)
void reduce_kernel(const float* __restrict__ acc, float* __restrict__ out) {
    __shared__ float sh[256];
    int tid = threadIdx.x;
    float sum = 0.0f;
    for (int n = tid; n < NROWS * NFREQ; n += 256) {
        int r = n / NFREQ, k = n % NFREQ;
        float num = 0.0f, den = 0.0f;
        #pragma unroll
        for (int rep = 0; rep < NREP; ++rep) {
            num += acc[rep * ACC_ELEMS + r * ACC_STRIDE + k];
            den += acc[rep * ACC_ELEMS + (NROWS + r) * ACC_STRIDE + k];
        }
        sum += num / den;
    }
    sh[tid] = sum;
    __syncthreads();
    for (int s = 128; s > 0; s >>= 1) {
        if (tid < s) sh[tid] += sh[tid + s];
        __syncthreads();
    }
    if (tid == 0) out[0] = sh[0] * (1.0f / 240.0f);
}

extern "C" void kernel_launch(void* const* d_in, const int* in_sizes, int n_in,
                              void* d_out, int out_size, void* d_ws, size_t ws_size,
                              hipStream_t stream) {
    const float* pred = (const float*)d_in[0];
    const float* target = (const float*)d_in[1];
    float* acc = (float*)d_ws;   // NREP replicas of [2][NROWS][ACC_STRIDE] = 256 KiB

    hipMemsetAsync(acc, 0, NREP * ACC_ELEMS * sizeof(float), stream);
    psd_kernel<<<NBLOCKS, 256, 0, stream>>>(pred, target, acc);
    reduce_kernel<<<1, 256, 0, stream>>>(acc, (float*)d_out);
}

// Round 3
// 168.958 us; speedup vs baseline: 1.6164x; 1.0299x over previous
//
#include <hip/hip_runtime.h>

#define NSEG 511
#define NROWS 8            // rows 8..15 only
#define ROW0 8
#define K0 21              // first needed freq bin
#define KEND 500           // bins k with 20 < k < 500
#define NFREQ 479
#define ACC_STRIDE 512     // padded per-row accumulator stride
#define ACC_ELEMS (2 * NROWS * ACC_STRIDE)   // one replica
#define NREP 8             // accumulator replicas
#define SPB 8              // segments per block (8 -> 1024 blocks = 4/CU, all resident)
#define NGROUPS 64         // ceil(511/8)
#define NBLOCKS (2 * NROWS * NGROUPS)

// XOR swizzle for the FFT buffer (keeps quads contiguous).
__device__ __forceinline__ int sw(int i) { return i ^ (((i >> 5) & 7) << 2); }
// Base-8 digit reversal: inverse of the stage-D output map m(n)=64(n&7)+8((n>>3)&7)+(n>>6).
__device__ __forceinline__ int revq(int m) { return 64 * (m & 7) + 8 * ((m >> 3) & 7) + (m >> 6); }

__device__ __forceinline__ float2 cmul(float2 a, float2 b) {
    return make_float2(fmaf(a.x, b.x, -a.y * b.y), fmaf(a.x, b.y, a.y * b.x));
}
__device__ __forceinline__ float2 cadd(float2 a, float2 b) { return make_float2(a.x + b.x, a.y + b.y); }
__device__ __forceinline__ float2 csub(float2 a, float2 b) { return make_float2(a.x - b.x, a.y - b.y); }

// In-register 8-point DFT (DIF).
__device__ __forceinline__ void dft8(float2& x0, float2& x1, float2& x2, float2& x3,
                                     float2& x4, float2& x5, float2& x6, float2& x7) {
    const float C45 = 0.70710678118654752440f;
    float2 t0 = cadd(x0, x4), u0 = csub(x0, x4);
    float2 t1 = cadd(x1, x5), u1 = csub(x1, x5);
    float2 t2 = cadd(x2, x6), u2 = csub(x2, x6);
    float2 t3 = cadd(x3, x7), u3 = csub(x3, x7);
    float2 s0 = cadd(t0, t2), d0 = csub(t0, t2);
    float2 s1 = cadd(t1, t3), d1 = csub(t1, t3);
    float2 v1 = make_float2(C45 * (u1.x + u1.y), C45 * (u1.y - u1.x));
    float2 v2 = make_float2(u2.y, -u2.x);
    float2 v3 = make_float2(C45 * (u3.y - u3.x), -C45 * (u3.x + u3.y));
    float2 s2 = cadd(u0, v2), d2 = csub(u0, v2);
    float2 s3 = cadd(v1, v3), d3 = csub(v1, v3);
    float2 mid1 = make_float2(d1.y, -d1.x);   // -i * d1
    float2 mid3 = make_float2(d3.y, -d3.x);   // -i * d3
    x0 = cadd(s0, s1); x4 = csub(s0, s1);
    x2 = cadd(d0, mid1); x6 = csub(d0, mid1);
    x1 = cadd(s2, s3); x5 = csub(s2, s3);
    x3 = cadd(d2, mid3); x7 = csub(d2, mid3);
}

// x[p] *= W^p with W = (c, s) given.
__device__ __forceinline__ void twiddle8cs(float2& x1, float2& x2, float2& x3, float2& x4,
                                           float2& x5, float2& x6, float2& x7,
                                           float c, float s) {
    float2 w1 = make_float2(c, s);
    float2 w2 = cmul(w1, w1);
    float2 w3 = cmul(w2, w1);
    float2 w4 = cmul(w2, w2);
    float2 w5 = cmul(w4, w1);
    float2 w6 = cmul(w3, w3);
    float2 w7 = cmul(w4, w3);
    x1 = cmul(x1, w1); x2 = cmul(x2, w2); x3 = cmul(x3, w3);
    x4 = cmul(x4, w4); x5 = cmul(x5, w5); x6 = cmul(x6, w6);
    x7 = cmul(x7, w7);
}

// One block = one (signal, row, 8 consecutive segments). Per segment: windowed
// 4096-pt real FFT via register 2048-pt complex FFT (radices [8,8,8,4-fused]).
// Power accumulated in registers across segments; ONE atomic flush per thread.
// Barrier schedule (3 per segment):
//   A -> sync -> B -> (no barrier, intra-wave) -> C -> sync -> untangle -> sync
// SPB=8 -> 1024 blocks = 4 blocks/CU demand: with the ~5-6 block residency cap
// every block is resident from t=0 (no ragged second dispatch round), and the
// prologue (8 global loads + 4 sincosf) amortizes over 8 segments.
// VGPR trim to hit the 80-reg granule (6 waves/SIMD): qA2/qB2 are immediate
// offsets of qA1/qB1 (provable for has2: k1<=243 -> revq(k+256)=revq(k)+4 and
// sw() preserves +16); cs1/sn1 recomputed per segment (asm touch defeats LICM).
// NOTE: __launch_bounds__(256) ONLY — forcing min-waves=6 made the allocator
// spill (VGPR 40, 165 MB scratch writes, 3x regression in round 1).
__global__ __launch_bounds__(256)
void psd_kernel(const float* __restrict__ pred,
                const float* __restrict__ target,
                float* __restrict__ acc) {
    __shared__ float2 buf[2048];   // 16 KiB FFT workspace

    const int bid = blockIdx.x;
    const int grp = bid % NGROUPS;
    const int row = (bid / NGROUPS) % NROWS + ROW0;
    const int sig = bid / (NGROUPS * NROWS);   // 0 = res (target-pred), 1 = target
    const int tid = threadIdx.x;
    const int seg0 = grp * SPB;
    const int ns = (seg0 + SPB <= NSEG) ? SPB : (NSEG - seg0);   // 8 (last group: 7)

    const float2* t2p = (const float2*)target;
    const float2* p2p = (const float2*)pred;

    // Complex point m of segment s: real samples at batch row 2(seg0+s)+(m>>9),
    // float2 offset row*512 + (m&511). m = tid + 256*R.
    const int base = 2 * seg0 * 8192 + row * 512 + tid;
#define LOADRAW(X, IDX)                                                      \
    {                                                                        \
        int _i = (IDX);                                                      \
        float2 v = t2p[_i];                                                  \
        if (sig == 0) { float2 p = p2p[_i]; v.x -= p.x; v.y -= p.y; }        \
        X = v;                                                               \
    }
    float2 r0, r1, r2, r3, r4, r5, r6, r7;
    LOADRAW(r0, base)
    LOADRAW(r1, base + 256)
    LOADRAW(r2, base + 8192)
    LOADRAW(r3, base + 8448)
    LOADRAW(r4, base + 16384)
    LOADRAW(r5, base + 16640)
    LOADRAW(r6, base + 24576)
    LOADRAW(r7, base + 24832)

    // ---- hoisted trig (segment-invariant) ----
    const float WA = 3.06796157577128245e-3f;      // 2*pi/2048
    const float H  = 0.70710678118654752440f;      // sqrt(2)/2
    float sa, ca;
    __sincosf((float)tid * WA, &sa, &ca);          // window base; stage-A tw = (ca,-sa)
    // stage-B twiddle base (depends on tid&31 only)
    float sb, cb;
    __sincosf((float)(tid & 31) * -2.45436926061702596e-2f, &sb, &cb);  // -2*pi/256
    // stage-C twiddle base (depends on tid&3 only): constants
    float cc, ss;
    {
        const float TC1 = 0.98078528040323044913f, TS1 = -0.19509032201612826785f;
        const float TC2 = 0.92387953251128675613f, TS2 = -0.38268343236508977173f;
        const float TC3 = 0.83146961230254523708f, TS3 = -0.55557023301960222474f;
        int mq = tid & 3;
        cc = (mq & 2) ? ((mq & 1) ? TC3 : TC2) : ((mq & 1) ? TC1 : 1.0f);
        ss = (mq & 2) ? ((mq & 1) ? TS3 : TS2) : ((mq & 1) ? TS1 : 0.0f);
    }

    // ---- permuted thread->bin map: sigma swaps the two low octal digits so
    // consecutive lanes vary the MIDDLE digit of k, spreading the
    // digit-reversed quad addresses across LDS bank groups.
    const int sigma = (tid & 0xC0) | ((tid & 7) << 3) | ((tid >> 3) & 7);
    const int k1 = K0 + sigma;                 // 21..276, always < 500
    const bool has2 = (sigma < KEND - K0 - 256);   // k2 = k1+256 < 500, k1 <= 243

    // untangle twiddle for bin k1 (k2's is derived per segment; saves 2 VGPRs)
    float sn0, cs0;
    __sincosf(-1.53398078788564123e-3f * (float)k1, &sn0, &cs0);  // -2*pi*k/4096

    // Untangle quad addresses (segment-invariant, float4 index into buf):
    // bin k needs X0 of quad m=k (Z[k]) and X3 of quad m=512-k (Z[2048-k]).
    // For has2 threads (k1 <= 243): quad(k1+256) = qA1+8, quad(512-(k1+256)) =
    // quad(256-k1) = qB1-8 — immediate offsets, no extra registers.
    const int qA1 = sw(4 * revq(k1)) >> 1;
    const int qB1 = sw(4 * revq(512 - k1)) >> 1;

    float pw1 = 0.0f, pw2 = 0.0f;   // register power accumulators (2 bins/thread)
    float4* b4 = (float4*)buf;

    #pragma unroll 1
    for (int s = 0; s < ns; ++s) {
        // ---- window coefficients: recomputed per segment (frees 16 persistent
        // VGPRs; asm touch defeats LICM so they stay transient)
        const float CD = 0.99999882344642529f;         // cos(pi/2048)
        const float SD = 1.53398018628476550e-3f;      // sin(pi/2048)
        float cat = ca, sat = sa;
        asm volatile("" : "+v"(cat), "+v"(sat));
        float2 wv0, wv1, wv2, wv3, wv4, wv5, wv6, wv7;
#define MKW(W, CE, SE) { float cr = (CE), sr = (SE);                         \
        W = make_float2(1.0f - cr, 1.0f - (cr * CD - sr * SD)); }
        MKW(wv0, cat, sat)
        MKW(wv1, H * (cat - sat), H * (sat + cat))
        MKW(wv2, -sat, cat)
        MKW(wv3, -H * (cat + sat), H * (cat - sat))
        MKW(wv4, -cat, -sat)
        MKW(wv5, H * (sat - cat), -H * (sat + cat))
        MKW(wv6, sat, -cat)
        MKW(wv7, H * (cat + sat), H * (sat - cat))
#undef MKW

        // ---- window raw -> x
        float2 x0 = make_float2(r0.x * wv0.x, r0.y * wv0.y);
        float2 x1 = make_float2(r1.x * wv1.x, r1.y * wv1.y);
        float2 x2 = make_float2(r2.x * wv2.x, r2.y * wv2.y);
        float2 x3 = make_float2(r3.x * wv3.x, r3.y * wv3.y);
        float2 x4 = make_float2(r4.x * wv4.x, r4.y * wv4.y);
        float2 x5 = make_float2(r5.x * wv5.x, r5.y * wv5.y);
        float2 x6 = make_float2(r6.x * wv6.x, r6.y * wv6.y);
        float2 x7 = make_float2(r7.x * wv7.x, r7.y * wv7.y);

        // ---- shift overlap half + prefetch next segment's new half (issued
        // now, consumed next iteration -> latency hidden under this FFT)
        if (s + 1 < ns) {
            r0 = r4; r1 = r5; r2 = r6; r3 = r7;
            int nb = base + (s + 1) * 16384;
            LOADRAW(r4, nb + 16384)
            LOADRAW(r5, nb + 16640)
            LOADRAW(r6, nb + 24576)
            LOADRAW(r7, nb + 24832)
        }

        // ---- stage A: radix-8 stride 256, twiddle W2048^{tid*p} = (ca,-sa)
        dft8(x0, x1, x2, x3, x4, x5, x6, x7);
        twiddle8cs(x1, x2, x3, x4, x5, x6, x7, ca, -sa);
        buf[sw(tid)]        = x0;
        buf[sw(tid + 256)]  = x1;
        buf[sw(tid + 512)]  = x2;
        buf[sw(tid + 768)]  = x3;
        buf[sw(tid + 1024)] = x4;
        buf[sw(tid + 1280)] = x5;
        buf[sw(tid + 1536)] = x6;
        buf[sw(tid + 1792)] = x7;
        __syncthreads();   // A->B crosses waves

        // ---- stage B: radix-8 stride 32 within each 256-subFFT
        {
            const int baseB = (tid & 31) + 256 * (tid >> 5);
            x0 = buf[sw(baseB)];
            x1 = buf[sw(baseB + 32)];
            x2 = buf[sw(baseB + 64)];
            x3 = buf[sw(baseB + 96)];
            x4 = buf[sw(baseB + 128)];
            x5 = buf[sw(baseB + 160)];
            x6 = buf[sw(baseB + 192)];
            x7 = buf[sw(baseB + 224)];
            dft8(x0, x1, x2, x3, x4, x5, x6, x7);
            twiddle8cs(x1, x2, x3, x4, x5, x6, x7, cb, sb);
            buf[sw(baseB)]       = x0;
            buf[sw(baseB + 32)]  = x1;
            buf[sw(baseB + 64)]  = x2;
            buf[sw(baseB + 96)]  = x3;
            buf[sw(baseB + 128)] = x4;
            buf[sw(baseB + 160)] = x5;
            buf[sw(baseB + 192)] = x6;
            buf[sw(baseB + 224)] = x7;
        }
        // NO barrier: B->C data flow is intra-wave (32-block t>>5 belongs to
        // wave t>>6 on both sides; lgkmcnt ordering suffices within a wave)

        // ---- stage C: radix-8 stride 4 within each 32-subFFT
        {
            const int baseC = (tid & 3) + 32 * ((tid >> 2) & 7) + 256 * (tid >> 5);
            x0 = buf[sw(baseC)];
            x1 = buf[sw(baseC + 4)];
            x2 = buf[sw(baseC + 8)];
            x3 = buf[sw(baseC + 12)];
            x4 = buf[sw(baseC + 16)];
            x5 = buf[sw(baseC + 20)];
            x6 = buf[sw(baseC + 24)];
            x7 = buf[sw(baseC + 28)];
            dft8(x0, x1, x2, x3, x4, x5, x6, x7);
            twiddle8cs(x1, x2, x3, x4, x5, x6, x7, cc, ss);
            buf[sw(baseC)]      = x0;
            buf[sw(baseC + 4)]  = x1;
            buf[sw(baseC + 8)]  = x2;
            buf[sw(baseC + 12)] = x3;
            buf[sw(baseC + 16)] = x4;
            buf[sw(baseC + 20)] = x5;
            buf[sw(baseC + 24)] = x6;
            buf[sw(baseC + 28)] = x7;
        }
        __syncthreads();   // C -> untangle crosses waves

        // ---- fused stage D + untangle: read the two quads for each bin
        // directly (quad n holds length-4 DFT inputs for bins 512v+m(n);
        // X0 = v=0 term = Z[m], X3 = v=3 term = Z[1536+m] = Z[2048-(512-m)]).
        {
            float4 lo = b4[qA1], hi = b4[qA1 + 1];
            float2 zk = make_float2((lo.x + hi.x) + (lo.z + hi.z),
                                    (lo.y + hi.y) + (lo.w + hi.w));
            lo = b4[qB1]; hi = b4[qB1 + 1];
            float D0x = lo.x - hi.x, D0y = lo.y - hi.y;
            float D1x = lo.z - hi.z, D1y = lo.w - hi.w;
            float2 zn = make_float2(D0x - D1y, D0y + D1x);
            float Ex = 0.5f * (zk.x + zn.x);
            float Ey = 0.5f * (zk.y - zn.y);
            float Ox = 0.5f * (zk.y + zn.y);
            float Oy = -0.5f * (zk.x - zn.x);
            float xr = Ex + Ox * cs0 - Oy * sn0;
            float xi = Ey + Ox * sn0 + Oy * cs0;
            pw1 += xr * xr + xi * xi;
        }
        if (has2) {
            // k2 = k1+256 untangle twiddle: rotate (cs0,sn0) by -pi/8.
            // Recomputed per segment from an asm-touched copy so cs1/sn1 are
            // not loop-carried registers.
            float c0 = cs0, s0 = sn0;
            asm volatile("" : "+v"(c0), "+v"(s0));
            const float CU = 0.98078528040323044913f;   // cos(pi/8)
            const float SU = 0.19509032201612826785f;   // sin(pi/8)
            float cs1 = c0 * CU + s0 * SU;
            float sn1 = s0 * CU - c0 * SU;
            float4 lo = b4[qA1 + 8], hi = b4[qA1 + 9];
            float2 zk = make_float2((lo.x + hi.x) + (lo.z + hi.z),
                                    (lo.y + hi.y) + (lo.w + hi.w));
            lo = b4[qB1 - 8]; hi = b4[qB1 - 7];
            float D0x = lo.x - hi.x, D0y = lo.y - hi.y;
            float D1x = lo.z - hi.z, D1y = lo.w - hi.w;
            float2 zn = make_float2(D0x - D1y, D0y + D1x);
            float Ex = 0.5f * (zk.x + zn.x);
            float Ey = 0.5f * (zk.y - zn.y);
            float Ox = 0.5f * (zk.y + zn.y);
            float Oy = -0.5f * (zk.x - zn.x);
            float xr = Ex + Ox * cs1 - Oy * sn1;
            float xi = Ey + Ox * sn1 + Oy * cs1;
            pw2 += xr * xr + xi * xi;
        }
        if (s + 1 < ns) __syncthreads();   // buf reuse by next stage A
    }

    // ---- single atomic flush per thread (atomics cut vs per-segment)
    {
        float* accR = acc + (bid & (NREP - 1)) * ACC_ELEMS;
        int i0 = (sig * NROWS + (row - ROW0)) * ACC_STRIDE;
        atomicAdd(&accR[i0 + sigma], pw1);
        if (has2) atomicAdd(&accR[i0 + 256 + sigma], pw2);
    }
#undef LOADRAW
}

// Single block: out = sum over (row,k) of P_res/P_tgt, / 240.
// (dfreq=1, scale=480, mean(last 8)*16 => 2/480 = 1/240; /T cancels in ratio)
__global__ __launch_bounds__(256)
void reduce_kernel(const float* __restrict__ acc, float* __restrict__ out) {
    __shared__ float sh[256];
    int tid = threadIdx.x;
    float sum = 0.0f;
    for (int n = tid; n < NROWS * NFREQ; n += 256) {
        int r = n / NFREQ, k = n % NFREQ;
        float num = 0.0f, den = 0.0f;
        #pragma unroll
        for (int rep = 0; rep < NREP; ++rep) {
            num += acc[rep * ACC_ELEMS + r * ACC_STRIDE + k];
            den += acc[rep * ACC_ELEMS + (NROWS + r) * ACC_STRIDE + k];
        }
        sum += num / den;
    }
    sh[tid] = sum;
    __syncthreads();
    for (int s = 128; s > 0; s >>= 1) {
        if (tid < s) sh[tid] += sh[tid + s];
        __syncthreads();
    }
    if (tid == 0) out[0] = sh[0] * (1.0f / 240.0f);
}

extern "C" void kernel_launch(void* const* d_in, const int* in_sizes, int n_in,
                              void* d_out, int out_size, void* d_ws, size_t ws_size,
                              hipStream_t stream) {
    const float* pred = (const float*)d_in[0];
    const float* target = (const float*)d_in[1];
    float* acc = (float*)d_ws;   // NREP replicas of [2][NROWS][ACC_STRIDE] = 256 KiB

    hipMemsetAsync(acc, 0, NREP * ACC_ELEMS * sizeof(float), stream);
    psd_kernel<<<NBLOCKS, 256, 0, stream>>>(pred, target, acc);
    reduce_kernel<<<1, 256, 0, stream>>>(acc, (float*)d_out);
}

// Round 4
// 163.464 us; speedup vs baseline: 1.6707x; 1.0336x over previous
//
#include <hip/hip_runtime.h>

#define NSEG 511
#define NROWS 8            // rows 8..15 only
#define ROW0 8
#define K0 21              // first needed freq bin
#define KEND 500           // bins k with 20 < k < 500
#define NFREQ 479
#define ACC_STRIDE 512     // padded per-row accumulator stride
#define ACC_ELEMS (2 * NROWS * ACC_STRIDE)   // one replica
#define NREP 8             // accumulator replicas
#define SPB 8              // segments per block (8 -> 1024 blocks = 4/CU, all resident)
#define NGROUPS 64         // ceil(511/8)
#define NBLOCKS (2 * NROWS * NGROUPS)

// XOR swizzle for the FFT buffer (stages A/B/C exchange).
__device__ __forceinline__ int sw(int i) { return i ^ (((i >> 5) & 7) << 2); }
// Natural-order plane address swizzle: injects m's bits 4-5 (the a>>1 digits
// that otherwise never reach the bank index) so stage-C scatter writes land
// exactly 4 lanes/bank-pair (wave64-b64 minimum) and untangle reads stay
// uniform. Plane stride 513 de-conflicts the r (slot) dimension.
__device__ __forceinline__ int natq(int m) { return m + 4 * ((m >> 4) & 3); }

__device__ __forceinline__ float2 cmul(float2 a, float2 b) {
    return make_float2(fmaf(a.x, b.x, -a.y * b.y), fmaf(a.x, b.y, a.y * b.x));
}
__device__ __forceinline__ float2 cadd(float2 a, float2 b) { return make_float2(a.x + b.x, a.y + b.y); }
__device__ __forceinline__ float2 csub(float2 a, float2 b) { return make_float2(a.x - b.x, a.y - b.y); }

// In-register 8-point DFT (DIF).
__device__ __forceinline__ void dft8(float2& x0, float2& x1, float2& x2, float2& x3,
                                     float2& x4, float2& x5, float2& x6, float2& x7) {
    const float C45 = 0.70710678118654752440f;
    float2 t0 = cadd(x0, x4), u0 = csub(x0, x4);
    float2 t1 = cadd(x1, x5), u1 = csub(x1, x5);
    float2 t2 = cadd(x2, x6), u2 = csub(x2, x6);
    float2 t3 = cadd(x3, x7), u3 = csub(x3, x7);
    float2 s0 = cadd(t0, t2), d0 = csub(t0, t2);
    float2 s1 = cadd(t1, t3), d1 = csub(t1, t3);
    float2 v1 = make_float2(C45 * (u1.x + u1.y), C45 * (u1.y - u1.x));
    float2 v2 = make_float2(u2.y, -u2.x);
    float2 v3 = make_float2(C45 * (u3.y - u3.x), -C45 * (u3.x + u3.y));
    float2 s2 = cadd(u0, v2), d2 = csub(u0, v2);
    float2 s3 = cadd(v1, v3), d3 = csub(v1, v3);
    float2 mid1 = make_float2(d1.y, -d1.x);   // -i * d1
    float2 mid3 = make_float2(d3.y, -d3.x);   // -i * d3
    x0 = cadd(s0, s1); x4 = csub(s0, s1);
    x2 = cadd(d0, mid1); x6 = csub(d0, mid1);
    x1 = cadd(s2, s3); x5 = csub(s2, s3);
    x3 = cadd(d2, mid3); x7 = csub(d2, mid3);
}

// x[p] *= W^p with W = (c, s) given.
__device__ __forceinline__ void twiddle8cs(float2& x1, float2& x2, float2& x3, float2& x4,
                                           float2& x5, float2& x6, float2& x7,
                                           float c, float s) {
    float2 w1 = make_float2(c, s);
    float2 w2 = cmul(w1, w1);
    float2 w3 = cmul(w2, w1);
    float2 w4 = cmul(w2, w2);
    float2 w5 = cmul(w4, w1);
    float2 w6 = cmul(w3, w3);
    float2 w7 = cmul(w4, w3);
    x1 = cmul(x1, w1); x2 = cmul(x2, w2); x3 = cmul(x3, w3);
    x4 = cmul(x4, w4); x5 = cmul(x5, w5); x6 = cmul(x6, w6);
    x7 = cmul(x7, w7);
}

// One block = one (signal, row, 8 consecutive segments). Per segment: windowed
// 4096-pt real FFT via register 2048-pt complex FFT (radices [8,8,8,4-fused]).
// Power accumulated in registers across segments; ONE atomic flush per thread.
//
// Barrier schedule (2 per segment, was 3):
//   A(buf writes) -> sync -> B(buf rt) -> [intra-wave] -> C(read buf, write
//   NAT planes) -> sync -> untangle(read nat) -> [no barrier] -> next A.
// Safety of the removed trailing barrier: all C(s) buf reads precede the
// C->untangle barrier, so A(s+1) buf writes (issued after it) cannot race
// them; C(s+1) nat writes are fenced from untangle(s) nat reads by the
// A->B barrier of segment s+1. nat and buf are disjoint regions.
//
// Stage C scatters its outputs straight into natural bin order:
// output position q=baseC+4p -> bin m=64p+8a+b (a=(tid>>2)&7, b=tid>>5),
// slot r=tid&3; nat addr = natq(m) + 513*r. Bank analysis: writes are
// exactly 4 lanes/bank-pair (minimum), untangle reads (consecutive m per
// lane) uniform. This removes the 8-16-way-conflicted b128 quad reads AND
// the sigma bin permutation of rounds 2-3.
//
// NOTE: __launch_bounds__(256) ONLY — forcing min-waves=6 made the allocator
// spill (VGPR 40, 165 MB scratch writes, 3x regression in round 1).
__global__ __launch_bounds__(256)
void psd_kernel(const float* __restrict__ pred,
                const float* __restrict__ target,
                float* __restrict__ acc) {
    __shared__ float2 buf[2048];   // 16 KiB FFT workspace
    __shared__ float2 nat[2064];   // 16.1 KiB natural-order planes (4 x 513 + swizzle pad)

    const int bid = blockIdx.x;
    const int grp = bid % NGROUPS;
    const int row = (bid / NGROUPS) % NROWS + ROW0;
    const int sig = bid / (NGROUPS * NROWS);   // 0 = res (target-pred), 1 = target
    const int tid = threadIdx.x;
    const int seg0 = grp * SPB;
    const int ns = (seg0 + SPB <= NSEG) ? SPB : (NSEG - seg0);   // 8 (last group: 7)

    const float2* t2p = (const float2*)target;
    const float2* p2p = (const float2*)pred;

    // Complex point m of segment s: real samples at batch row 2(seg0+s)+(m>>9),
    // float2 offset row*512 + (m&511). m = tid + 256*R.
    const int base = 2 * seg0 * 8192 + row * 512 + tid;
#define LOADRAW(X, IDX)                                                      \
    {                                                                        \
        int _i = (IDX);                                                      \
        float2 v = t2p[_i];                                                  \
        if (sig == 0) { float2 p = p2p[_i]; v.x -= p.x; v.y -= p.y; }        \
        X = v;                                                               \
    }
    float2 r0, r1, r2, r3, r4, r5, r6, r7;
    LOADRAW(r0, base)
    LOADRAW(r1, base + 256)
    LOADRAW(r2, base + 8192)
    LOADRAW(r3, base + 8448)
    LOADRAW(r4, base + 16384)
    LOADRAW(r5, base + 16640)
    LOADRAW(r6, base + 24576)
    LOADRAW(r7, base + 24832)

    // ---- hoisted trig (segment-invariant) ----
    const float WA = 3.06796157577128245e-3f;      // 2*pi/2048
    const float H  = 0.70710678118654752440f;      // sqrt(2)/2
    float sa, ca;
    __sincosf((float)tid * WA, &sa, &ca);          // window base; stage-A tw = (ca,-sa)
    // stage-B twiddle base (depends on tid&31 only)
    float sb, cb;
    __sincosf((float)(tid & 31) * -2.45436926061702596e-2f, &sb, &cb);  // -2*pi/256
    // stage-C twiddle base (depends on tid&3 only): constants
    float cc, ss;
    {
        const float TC1 = 0.98078528040323044913f, TS1 = -0.19509032201612826785f;
        const float TC2 = 0.92387953251128675613f, TS2 = -0.38268343236508977173f;
        const float TC3 = 0.83146961230254523708f, TS3 = -0.55557023301960222474f;
        int mq = tid & 3;
        cc = (mq & 2) ? ((mq & 1) ? TC3 : TC2) : ((mq & 1) ? TC1 : 1.0f);
        ss = (mq & 2) ? ((mq & 1) ? TS3 : TS2) : ((mq & 1) ? TS1 : 0.0f);
    }

    const int k1 = K0 + tid;                       // 21..276, always < 500
    const bool has2 = (tid < KEND - K0 - 256);     // k2 = k1+256 < 500, k1 <= 243

    // untangle twiddle for bin k1 (k2's is derived per segment; saves regs)
    float sn0, cs0;
    __sincosf(-1.53398078788564123e-3f * (float)k1, &sn0, &cs0);  // -2*pi*k/4096

    // Natural-plane base addresses (segment-invariant). Bin k needs slot-sums
    // of quad m=k (X0 = Z[k]) and quad m=512-k (X3 = Z[2048-k]).
    // k2=k1+256 variants are immediate +/-256 offsets: natq(m+256)=natq(m)+256
    // because ((m+256)>>4)&3 == (m>>4)&3.
    const int qk = natq(k1);
    const int qn = natq(512 - k1);

    // Stage-C scatter base: bin m = 64p + mb, slot r = tid&3.
    const int mb = 8 * ((tid >> 2) & 7) + (tid >> 5);       // 8a + b
    const int natC = natq(mb) + 513 * (tid & 3);            // natq(64p+mb)=natq(mb)+64p

    float pw1 = 0.0f, pw2 = 0.0f;   // register power accumulators (2 bins/thread)

    #pragma unroll 1
    for (int s = 0; s < ns; ++s) {
        // ---- window coefficients: recomputed per segment (asm touch defeats
        // LICM so they stay transient, not loop-carried)
        const float CD = 0.99999882344642529f;         // cos(pi/2048)
        const float SD = 1.53398018628476550e-3f;      // sin(pi/2048)
        float cat = ca, sat = sa;
        asm volatile("" : "+v"(cat), "+v"(sat));
        float2 wv0, wv1, wv2, wv3, wv4, wv5, wv6, wv7;
#define MKW(W, CE, SE) { float cr = (CE), sr = (SE);                         \
        W = make_float2(1.0f - cr, 1.0f - (cr * CD - sr * SD)); }
        MKW(wv0, cat, sat)
        MKW(wv1, H * (cat - sat), H * (sat + cat))
        MKW(wv2, -sat, cat)
        MKW(wv3, -H * (cat + sat), H * (cat - sat))
        MKW(wv4, -cat, -sat)
        MKW(wv5, H * (sat - cat), -H * (sat + cat))
        MKW(wv6, sat, -cat)
        MKW(wv7, H * (cat + sat), H * (sat - cat))
#undef MKW

        // ---- window raw -> x
        float2 x0 = make_float2(r0.x * wv0.x, r0.y * wv0.y);
        float2 x1 = make_float2(r1.x * wv1.x, r1.y * wv1.y);
        float2 x2 = make_float2(r2.x * wv2.x, r2.y * wv2.y);
        float2 x3 = make_float2(r3.x * wv3.x, r3.y * wv3.y);
        float2 x4 = make_float2(r4.x * wv4.x, r4.y * wv4.y);
        float2 x5 = make_float2(r5.x * wv5.x, r5.y * wv5.y);
        float2 x6 = make_float2(r6.x * wv6.x, r6.y * wv6.y);
        float2 x7 = make_float2(r7.x * wv7.x, r7.y * wv7.y);

        // ---- shift overlap half + prefetch next segment's new half (issued
        // now, consumed next iteration -> latency hidden under this FFT)
        if (s + 1 < ns) {
            r0 = r4; r1 = r5; r2 = r6; r3 = r7;
            int nb = base + (s + 1) * 16384;
            LOADRAW(r4, nb + 16384)
            LOADRAW(r5, nb + 16640)
            LOADRAW(r6, nb + 24576)
            LOADRAW(r7, nb + 24832)
        }

        // ---- stage A: radix-8 stride 256, twiddle W2048^{tid*p} = (ca,-sa)
        dft8(x0, x1, x2, x3, x4, x5, x6, x7);
        twiddle8cs(x1, x2, x3, x4, x5, x6, x7, ca, -sa);
        buf[sw(tid)]        = x0;
        buf[sw(tid + 256)]  = x1;
        buf[sw(tid + 512)]  = x2;
        buf[sw(tid + 768)]  = x3;
        buf[sw(tid + 1024)] = x4;
        buf[sw(tid + 1280)] = x5;
        buf[sw(tid + 1536)] = x6;
        buf[sw(tid + 1792)] = x7;
        __syncthreads();   // A->B crosses waves

        // ---- stage B: radix-8 stride 32 within each 256-subFFT
        {
            const int baseB = (tid & 31) + 256 * (tid >> 5);
            x0 = buf[sw(baseB)];
            x1 = buf[sw(baseB + 32)];
            x2 = buf[sw(baseB + 64)];
            x3 = buf[sw(baseB + 96)];
            x4 = buf[sw(baseB + 128)];
            x5 = buf[sw(baseB + 160)];
            x6 = buf[sw(baseB + 192)];
            x7 = buf[sw(baseB + 224)];
            dft8(x0, x1, x2, x3, x4, x5, x6, x7);
            twiddle8cs(x1, x2, x3, x4, x5, x6, x7, cb, sb);
            buf[sw(baseB)]       = x0;
            buf[sw(baseB + 32)]  = x1;
            buf[sw(baseB + 64)]  = x2;
            buf[sw(baseB + 96)]  = x3;
            buf[sw(baseB + 128)] = x4;
            buf[sw(baseB + 160)] = x5;
            buf[sw(baseB + 192)] = x6;
            buf[sw(baseB + 224)] = x7;
        }
        // NO barrier: B->C data flow is intra-wave (32-block t>>5 belongs to
        // wave t>>6 on both sides; lgkmcnt ordering suffices within a wave)

        // ---- stage C: radix-8 stride 4; outputs scattered straight into
        // natural bin order (fused digit reversal), conflict-free by natq.
        {
            const int baseC = (tid & 3) + 32 * ((tid >> 2) & 7) + 256 * (tid >> 5);
            x0 = buf[sw(baseC)];
            x1 = buf[sw(baseC + 4)];
            x2 = buf[sw(baseC + 8)];
            x3 = buf[sw(baseC + 12)];
            x4 = buf[sw(baseC + 16)];
            x5 = buf[sw(baseC + 20)];
            x6 = buf[sw(baseC + 24)];
            x7 = buf[sw(baseC + 28)];
            dft8(x0, x1, x2, x3, x4, x5, x6, x7);
            twiddle8cs(x1, x2, x3, x4, x5, x6, x7, cc, ss);
            nat[natC]       = x0;
            nat[natC + 64]  = x1;
            nat[natC + 128] = x2;
            nat[natC + 192] = x3;
            nat[natC + 256] = x4;
            nat[natC + 320] = x5;
            nat[natC + 384] = x6;
            nat[natC + 448] = x7;
        }
        __syncthreads();   // C -> untangle crosses waves

        // ---- fused radix-4 + untangle from natural planes:
        // X0(m) = v0+v1+v2+v3 ; X3(m) = (v0-v2) - i*(v1-v3) combined as
        // (D0x - D1y, D0y + D1x). zk = X0(k), zn = X3(512-k) = Z[2048-k].
        {
            float2 a0 = nat[qk],        a1 = nat[qk + 513];
            float2 a2 = nat[qk + 1026], a3 = nat[qk + 1539];
            float2 zk = make_float2((a0.x + a1.x) + (a2.x + a3.x),
                                    (a0.y + a1.y) + (a2.y + a3.y));
            float2 b0 = nat[qn],        b1 = nat[qn + 513];
            float2 b2 = nat[qn + 1026], b3 = nat[qn + 1539];
            float D0x = b0.x - b2.x, D0y = b0.y - b2.y;
            float D1x = b1.x - b3.x, D1y = b1.y - b3.y;
            float2 zn = make_float2(D0x - D1y, D0y + D1x);
            float Ex = 0.5f * (zk.x + zn.x);
            float Ey = 0.5f * (zk.y - zn.y);
            float Ox = 0.5f * (zk.y + zn.y);
            float Oy = -0.5f * (zk.x - zn.x);
            float xr = Ex + Ox * cs0 - Oy * sn0;
            float xi = Ey + Ox * sn0 + Oy * cs0;
            pw1 += xr * xr + xi * xi;
        }
        if (has2) {
            // k2 = k1+256 untangle twiddle: rotate (cs0,sn0) by -pi/8,
            // recomputed per segment (asm touch) so it isn't loop-carried.
            float c0 = cs0, s0 = sn0;
            asm volatile("" : "+v"(c0), "+v"(s0));
            const float CU = 0.98078528040323044913f;   // cos(pi/8)
            const float SU = 0.19509032201612826785f;   // sin(pi/8)
            float cs1 = c0 * CU + s0 * SU;
            float sn1 = s0 * CU - c0 * SU;
            float2 a0 = nat[qk + 256],  a1 = nat[qk + 769];
            float2 a2 = nat[qk + 1282], a3 = nat[qk + 1795];
            float2 zk = make_float2((a0.x + a1.x) + (a2.x + a3.x),
                                    (a0.y + a1.y) + (a2.y + a3.y));
            float2 b0 = nat[qn - 256],  b1 = nat[qn + 257];
            float2 b2 = nat[qn + 770],  b3 = nat[qn + 1283];
            float D0x = b0.x - b2.x, D0y = b0.y - b2.y;
            float D1x = b1.x - b3.x, D1y = b1.y - b3.y;
            float2 zn = make_float2(D0x - D1y, D0y + D1x);
            float Ex = 0.5f * (zk.x + zn.x);
            float Ey = 0.5f * (zk.y - zn.y);
            float Ox = 0.5f * (zk.y + zn.y);
            float Oy = -0.5f * (zk.x - zn.x);
            float xr = Ex + Ox * cs1 - Oy * sn1;
            float xi = Ey + Ox * sn1 + Oy * cs1;
            pw2 += xr * xr + xi * xi;
        }
        // NO trailing barrier: buf was last read before the C->untangle
        // barrier; nat is protected by the next iteration's A->B barrier.
    }

    // ---- single atomic flush per thread (atomics cut vs per-segment)
    {
        float* accR = acc + (bid & (NREP - 1)) * ACC_ELEMS;
        int i0 = (sig * NROWS + (row - ROW0)) * ACC_STRIDE;
        atomicAdd(&accR[i0 + tid], pw1);
        if (has2) atomicAdd(&accR[i0 + 256 + tid], pw2);
    }
#undef LOADRAW
}

// Single block: out = sum over (row,k) of P_res/P_tgt, / 240.
// (dfreq=1, scale=480, mean(last 8)*16 => 2/480 = 1/240; /T cancels in ratio)
__global__ __launch_bounds__(256)
void reduce_kernel(const float* __restrict__ acc, float* __restrict__ out) {
    __shared__ float sh[256];
    int tid = threadIdx.x;
    float sum = 0.0f;
    for (int n = tid; n < NROWS * NFREQ; n += 256) {
        int r = n / NFREQ, k = n % NFREQ;
        float num = 0.0f, den = 0.0f;
        #pragma unroll
        for (int rep = 0; rep < NREP; ++rep) {
            num += acc[rep * ACC_ELEMS + r * ACC_STRIDE + k];
            den += acc[rep * ACC_ELEMS + (NROWS + r) * ACC_STRIDE + k];
        }
        sum += num / den;
    }
    sh[tid] = sum;
    __syncthreads();
    for (int s = 128; s > 0; s >>= 1) {
        if (tid < s) sh[tid] += sh[tid + s];
        __syncthreads();
    }
    if (tid == 0) out[0] = sh[0] * (1.0f / 240.0f);
}

extern "C" void kernel_launch(void* const* d_in, const int* in_sizes, int n_in,
                              void* d_out, int out_size, void* d_ws, size_t ws_size,
                              hipStream_t stream) {
    const float* pred = (const float*)d_in[0];
    const float* target = (const float*)d_in[1];
    float* acc = (float*)d_ws;   // NREP replicas of [2][NROWS][ACC_STRIDE] = 256 KiB

    hipMemsetAsync(acc, 0, NREP * ACC_ELEMS * sizeof(float), stream);
    psd_kernel<<<NBLOCKS, 256, 0, stream>>>(pred, target, acc);
    reduce_kernel<<<1, 256, 0, stream>>>(acc, (float*)d_out);
}

// Round 5
// 161.357 us; speedup vs baseline: 1.6925x; 1.0131x over previous
//
#include <hip/hip_runtime.h>

#define NSEG 511
#define NROWS 8            // rows 8..15 only
#define ROW0 8
#define K0 21              // first needed freq bin
#define KEND 500           // bins k with 20 < k < 500
#define NFREQ 479
#define ACC_STRIDE 512     // padded per-row accumulator stride
#define ACC_ELEMS (2 * NROWS * ACC_STRIDE)   // one replica
#define NREP 8             // accumulator replicas
#define SPB 8              // segments per block (8 -> 1024 blocks = 4/CU)
#define NGROUPS 64         // ceil(511/8)
#define NBLOCKS (2 * NROWS * NGROUPS)

// XOR swizzle for the FFT buffer (stages A/B/C exchange).
__device__ __forceinline__ int sw(int i) { return i ^ (((i >> 5) & 7) << 2); }
// Natural-order bin map, per r-plane: nsw(m) = m ^ (((m>>4)&3)<<2).
// BIJECTIVE on [0,512) (bits 4-5 untouched -> m recoverable), unlike round-4's
// additive natq which collided (natq(52)==natq(64)). Full address =
// 512*r + (nsw(m) ^ r): the ^r (bits 0-1) plus the bits4-5 injection (bits 2-3)
// makes stage-C scatter writes land EXACTLY 4 lanes/bank-pair (b64 minimum),
// and untangle reads (consecutive m, fixed r per instr) stay uniform.
// Preserves immediate-offset structure: addr(m+64p,r)=addr(m,r)+64p,
// addr(m+-256,r)=addr(m,r)+-256.
__device__ __forceinline__ int nsw(int m) { return m ^ (((m >> 4) & 3) << 2); }

__device__ __forceinline__ float2 cmul(float2 a, float2 b) {
    return make_float2(fmaf(a.x, b.x, -a.y * b.y), fmaf(a.x, b.y, a.y * b.x));
}
__device__ __forceinline__ float2 cadd(float2 a, float2 b) { return make_float2(a.x + b.x, a.y + b.y); }
__device__ __forceinline__ float2 csub(float2 a, float2 b) { return make_float2(a.x - b.x, a.y - b.y); }

// In-register 8-point DFT (DIF).
__device__ __forceinline__ void dft8(float2& x0, float2& x1, float2& x2, float2& x3,
                                     float2& x4, float2& x5, float2& x6, float2& x7) {
    const float C45 = 0.70710678118654752440f;
    float2 t0 = cadd(x0, x4), u0 = csub(x0, x4);
    float2 t1 = cadd(x1, x5), u1 = csub(x1, x5);
    float2 t2 = cadd(x2, x6), u2 = csub(x2, x6);
    float2 t3 = cadd(x3, x7), u3 = csub(x3, x7);
    float2 s0 = cadd(t0, t2), d0 = csub(t0, t2);
    float2 s1 = cadd(t1, t3), d1 = csub(t1, t3);
    float2 v1 = make_float2(C45 * (u1.x + u1.y), C45 * (u1.y - u1.x));
    float2 v2 = make_float2(u2.y, -u2.x);
    float2 v3 = make_float2(C45 * (u3.y - u3.x), -C45 * (u3.x + u3.y));
    float2 s2 = cadd(u0, v2), d2 = csub(u0, v2);
    float2 s3 = cadd(v1, v3), d3 = csub(v1, v3);
    float2 mid1 = make_float2(d1.y, -d1.x);   // -i * d1
    float2 mid3 = make_float2(d3.y, -d3.x);   // -i * d3
    x0 = cadd(s0, s1); x4 = csub(s0, s1);
    x2 = cadd(d0, mid1); x6 = csub(d0, mid1);
    x1 = cadd(s2, s3); x5 = csub(s2, s3);
    x3 = cadd(d2, mid3); x7 = csub(d2, mid3);
}

// Build w^1..w^7 from w = (c,s). Hoisted pre-loop (segment-invariant).
__device__ __forceinline__ void twbuild(float c, float s,
                                        float2& w1, float2& w2, float2& w3, float2& w4,
                                        float2& w5, float2& w6, float2& w7) {
    w1 = make_float2(c, s);
    w2 = cmul(w1, w1);
    w3 = cmul(w2, w1);
    w4 = cmul(w2, w2);
    w5 = cmul(w4, w1);
    w6 = cmul(w3, w3);
    w7 = cmul(w4, w3);
}
// Apply precomputed twiddles.
__device__ __forceinline__ void twapply(float2& x1, float2& x2, float2& x3, float2& x4,
                                        float2& x5, float2& x6, float2& x7,
                                        float2 w1, float2 w2, float2 w3, float2 w4,
                                        float2 w5, float2 w6, float2 w7) {
    x1 = cmul(x1, w1); x2 = cmul(x2, w2); x3 = cmul(x3, w3);
    x4 = cmul(x4, w4); x5 = cmul(x5, w5); x6 = cmul(x6, w6);
    x7 = cmul(x7, w7);
}

// One block = one (signal, row, 8 consecutive segments). Per segment: windowed
// 4096-pt real FFT via register 2048-pt complex FFT (radices [8,8,8,4-fused]).
// Power accumulated in registers across segments; ONE atomic flush per thread.
//
// Barrier schedule (2 per segment), re-ordered for pipe mixing:
//   prologue: A(0) -> barrier
//   loop s:   B(s) -> [intra-wave] -> C(s, write nat) -> barrier
//             -> A(s+1) (pure VALU + buf writes) + untangle(s) (nat reads)
//             -> barrier (skipped on last iter)
// A(s+1) and untangle(s) share a window: A's VALU overlaps untangle's LDS
// reads. Safety: buf/nat disjoint; the mid barrier fences C-writes->untangle-
// reads and C-buf-reads->A-writes; the closing barrier fences A-writes->
// B-reads and untangle-reads->C(s+1)-writes.
//
// All segment-invariant VALU (window coeffs, stage-A/B twiddle chains, cs/sn
// untangle twiddles) hoisted pre-loop; VGPR headroom is free because LDS
// (32 KiB exactly) caps residency at 4-5 blocks/CU (16-20 waves).
// NOTE: __launch_bounds__(256) ONLY — forcing min-waves made the allocator
// spill (round 1: VGPR 40, 165 MB scratch, 3x regression).
__global__ __launch_bounds__(256)
void psd_kernel(const float* __restrict__ pred,
                const float* __restrict__ target,
                float* __restrict__ acc) {
    __shared__ float2 buf[2048];   // 16 KiB FFT workspace
    __shared__ float2 nat[2048];   // 16 KiB natural-order planes (4 x 512, XOR map)

    const int bid = blockIdx.x;
    const int grp = bid % NGROUPS;
    const int row = (bid / NGROUPS) % NROWS + ROW0;
    const int sig = bid / (NGROUPS * NROWS);   // 0 = res (target-pred), 1 = target
    const int tid = threadIdx.x;
    const int seg0 = grp * SPB;
    const int ns = (seg0 + SPB <= NSEG) ? SPB : (NSEG - seg0);   // 8 (last group: 7)

    const float2* t2p = (const float2*)target;
    const float2* p2p = (const float2*)pred;

    // Complex point m of segment s: real samples at batch row 2(seg0+s)+(m>>9),
    // float2 offset row*512 + (m&511). m = tid + 256*R.
    const int base = 2 * seg0 * 8192 + row * 512 + tid;
#define LOADRAW(X, IDX)                                                      \
    {                                                                        \
        int _i = (IDX);                                                      \
        float2 v = t2p[_i];                                                  \
        if (sig == 0) { float2 p = p2p[_i]; v.x -= p.x; v.y -= p.y; }        \
        X = v;                                                               \
    }
    float2 r0, r1, r2, r3, r4, r5, r6, r7;
    LOADRAW(r0, base)
    LOADRAW(r1, base + 256)
    LOADRAW(r2, base + 8192)
    LOADRAW(r3, base + 8448)
    LOADRAW(r4, base + 16384)
    LOADRAW(r5, base + 16640)
    LOADRAW(r6, base + 24576)
    LOADRAW(r7, base + 24832)

    // ---- hoisted trig + twiddles (segment-invariant; overlaps load latency) ----
    const float WA = 3.06796157577128245e-3f;      // 2*pi/2048
    const float CD = 0.99999882344642529f;         // cos(pi/2048)
    const float SD = 1.53398018628476550e-3f;      // sin(pi/2048)
    const float H  = 0.70710678118654752440f;      // sqrt(2)/2
    float sa, ca;
    __sincosf((float)tid * WA, &sa, &ca);          // window base; stage-A tw = (ca,-sa)
    // window weights per R (rotations of (ca,sa) by R*pi/4), w = (even, odd)
    float2 wv0, wv1, wv2, wv3, wv4, wv5, wv6, wv7;
#define MKW(W, CE, SE) { float cr = (CE), sr = (SE);                         \
        W = make_float2(1.0f - cr, 1.0f - (cr * CD - sr * SD)); }
    MKW(wv0, ca, sa)
    MKW(wv1, H * (ca - sa), H * (sa + ca))
    MKW(wv2, -sa, ca)
    MKW(wv3, -H * (ca + sa), H * (ca - sa))
    MKW(wv4, -ca, -sa)
    MKW(wv5, H * (sa - ca), -H * (sa + ca))
    MKW(wv6, sa, -ca)
    MKW(wv7, H * (ca + sa), H * (sa - ca))
#undef MKW
    // stage-A twiddle chain (base (ca,-sa))
    float2 wA1, wA2, wA3, wA4, wA5, wA6, wA7;
    twbuild(ca, -sa, wA1, wA2, wA3, wA4, wA5, wA6, wA7);
    // stage-B twiddle chain (depends on tid&31 only)
    {
        float sb, cb;
        __sincosf((float)(tid & 31) * -2.45436926061702596e-2f, &sb, &cb);  // -2*pi/256
        sa = sb; ca = cb;   // reuse regs
    }
    float2 wB1, wB2, wB3, wB4, wB5, wB6, wB7;
    twbuild(ca, sa, wB1, wB2, wB3, wB4, wB5, wB6, wB7);
    // stage-C twiddle base (depends on tid&3 only): constants
    float cc, ss;
    {
        const float TC1 = 0.98078528040323044913f, TS1 = -0.19509032201612826785f;
        const float TC2 = 0.92387953251128675613f, TS2 = -0.38268343236508977173f;
        const float TC3 = 0.83146961230254523708f, TS3 = -0.55557023301960222474f;
        int mq = tid & 3;
        cc = (mq & 2) ? ((mq & 1) ? TC3 : TC2) : ((mq & 1) ? TC1 : 1.0f);
        ss = (mq & 2) ? ((mq & 1) ? TS3 : TS2) : ((mq & 1) ? TS1 : 0.0f);
    }
    float2 wC1, wC2, wC3, wC4, wC5, wC6, wC7;
    twbuild(cc, ss, wC1, wC2, wC3, wC4, wC5, wC6, wC7);

    const int k1 = K0 + tid;                       // 21..276, always < 500
    const bool has2 = (tid < KEND - K0 - 256);     // k2 = k1+256 < 500, k1 <= 243

    // untangle twiddles for bins k1 and k2 = k1+256 (-pi/8 rotation)
    float sn0, cs0, sn1, cs1;
    __sincosf(-1.53398078788564123e-3f * (float)k1, &sn0, &cs0);  // -2*pi*k/4096
    {
        const float CU = 0.98078528040323044913f;   // cos(pi/8)
        const float SU = 0.19509032201612826785f;   // sin(pi/8)
        cs1 = cs0 * CU + sn0 * SU;
        sn1 = sn0 * CU - cs0 * SU;
    }

    // Natural-plane base addresses (segment-invariant). Bin k needs slot r
    // values of quad m=k (X0 -> Z[k]) and m=512-k (X3 -> Z[2048-k]) at
    // 512r + (nsw(m)^r). k2 = k1+256 variants are +/-256 immediate offsets.
    const int qk0 = nsw(k1);
    const int qn0 = nsw(512 - k1);

    // Stage-C scatter base: bin m = 64p + mb, slot r = tid&3.
    const int mb = 8 * ((tid >> 2) & 7) + (tid >> 5);
    const int natC = (nsw(mb) ^ (tid & 3)) + 512 * (tid & 3);

    float pw1 = 0.0f, pw2 = 0.0f;   // register power accumulators (2 bins/thread)

    // ---- prologue: stage A for segment 0 ----
    {
        float2 x0 = make_float2(r0.x * wv0.x, r0.y * wv0.y);
        float2 x1 = make_float2(r1.x * wv1.x, r1.y * wv1.y);
        float2 x2 = make_float2(r2.x * wv2.x, r2.y * wv2.y);
        float2 x3 = make_float2(r3.x * wv3.x, r3.y * wv3.y);
        float2 x4 = make_float2(r4.x * wv4.x, r4.y * wv4.y);
        float2 x5 = make_float2(r5.x * wv5.x, r5.y * wv5.y);
        float2 x6 = make_float2(r6.x * wv6.x, r6.y * wv6.y);
        float2 x7 = make_float2(r7.x * wv7.x, r7.y * wv7.y);
        if (ns > 1) {   // prefetch segment 1's new half
            r0 = r4; r1 = r5; r2 = r6; r3 = r7;
            int nb = base + 16384;
            LOADRAW(r4, nb + 16384)
            LOADRAW(r5, nb + 16640)
            LOADRAW(r6, nb + 24576)
            LOADRAW(r7, nb + 24832)
        }
        dft8(x0, x1, x2, x3, x4, x5, x6, x7);
        twapply(x1, x2, x3, x4, x5, x6, x7, wA1, wA2, wA3, wA4, wA5, wA6, wA7);
        buf[sw(tid)]        = x0;
        buf[sw(tid + 256)]  = x1;
        buf[sw(tid + 512)]  = x2;
        buf[sw(tid + 768)]  = x3;
        buf[sw(tid + 1024)] = x4;
        buf[sw(tid + 1280)] = x5;
        buf[sw(tid + 1536)] = x6;
        buf[sw(tid + 1792)] = x7;
    }
    __syncthreads();

    #pragma unroll 1
    for (int s = 0; s < ns; ++s) {
        // ---- stage B: radix-8 stride 32 within each 256-subFFT
        {
            const int baseB = (tid & 31) + 256 * (tid >> 5);
            float2 x0 = buf[sw(baseB)];
            float2 x1 = buf[sw(baseB + 32)];
            float2 x2 = buf[sw(baseB + 64)];
            float2 x3 = buf[sw(baseB + 96)];
            float2 x4 = buf[sw(baseB + 128)];
            float2 x5 = buf[sw(baseB + 160)];
            float2 x6 = buf[sw(baseB + 192)];
            float2 x7 = buf[sw(baseB + 224)];
            dft8(x0, x1, x2, x3, x4, x5, x6, x7);
            twapply(x1, x2, x3, x4, x5, x6, x7, wB1, wB2, wB3, wB4, wB5, wB6, wB7);
            buf[sw(baseB)]       = x0;
            buf[sw(baseB + 32)]  = x1;
            buf[sw(baseB + 64)]  = x2;
            buf[sw(baseB + 96)]  = x3;
            buf[sw(baseB + 128)] = x4;
            buf[sw(baseB + 160)] = x5;
            buf[sw(baseB + 192)] = x6;
            buf[sw(baseB + 224)] = x7;
        }
        // NO barrier: B->C data flow is intra-wave (32-block t>>5 belongs to
        // wave t>>6 on both sides; lgkmcnt ordering suffices within a wave)

        // ---- stage C: radix-8 stride 4; outputs scattered straight into
        // natural bin order (fused digit reversal), conflict-free via nsw^r.
        {
            const int baseC = (tid & 3) + 32 * ((tid >> 2) & 7) + 256 * (tid >> 5);
            float2 x0 = buf[sw(baseC)];
            float2 x1 = buf[sw(baseC + 4)];
            float2 x2 = buf[sw(baseC + 8)];
            float2 x3 = buf[sw(baseC + 12)];
            float2 x4 = buf[sw(baseC + 16)];
            float2 x5 = buf[sw(baseC + 20)];
            float2 x6 = buf[sw(baseC + 24)];
            float2 x7 = buf[sw(baseC + 28)];
            dft8(x0, x1, x2, x3, x4, x5, x6, x7);
            twapply(x1, x2, x3, x4, x5, x6, x7, wC1, wC2, wC3, wC4, wC5, wC6, wC7);
            nat[natC]       = x0;
            nat[natC + 64]  = x1;
            nat[natC + 128] = x2;
            nat[natC + 192] = x3;
            nat[natC + 256] = x4;
            nat[natC + 320] = x5;
            nat[natC + 384] = x6;
            nat[natC + 448] = x7;
        }
        __syncthreads();   // C-writes -> untangle-reads; C-buf-reads -> A-writes

        // ---- stage A for segment s+1 (same window as untangle: A's VALU
        // overlaps untangle's LDS reads; buf/nat disjoint)
        if (s + 1 < ns) {
            float2 x0 = make_float2(r0.x * wv0.x, r0.y * wv0.y);
            float2 x1 = make_float2(r1.x * wv1.x, r1.y * wv1.y);
            float2 x2 = make_float2(r2.x * wv2.x, r2.y * wv2.y);
            float2 x3 = make_float2(r3.x * wv3.x, r3.y * wv3.y);
            float2 x4 = make_float2(r4.x * wv4.x, r4.y * wv4.y);
            float2 x5 = make_float2(r5.x * wv5.x, r5.y * wv5.y);
            float2 x6 = make_float2(r6.x * wv6.x, r6.y * wv6.y);
            float2 x7 = make_float2(r7.x * wv7.x, r7.y * wv7.y);
            if (s + 2 < ns) {   // prefetch segment s+2's new half
                r0 = r4; r1 = r5; r2 = r6; r3 = r7;
                int nb = base + (s + 2) * 16384;
                LOADRAW(r4, nb + 16384)
                LOADRAW(r5, nb + 16640)
                LOADRAW(r6, nb + 24576)
                LOADRAW(r7, nb + 24832)
            }
            dft8(x0, x1, x2, x3, x4, x5, x6, x7);
            twapply(x1, x2, x3, x4, x5, x6, x7, wA1, wA2, wA3, wA4, wA5, wA6, wA7);
            buf[sw(tid)]        = x0;
            buf[sw(tid + 256)]  = x1;
            buf[sw(tid + 512)]  = x2;
            buf[sw(tid + 768)]  = x3;
            buf[sw(tid + 1024)] = x4;
            buf[sw(tid + 1280)] = x5;
            buf[sw(tid + 1536)] = x6;
            buf[sw(tid + 1792)] = x7;
        }

        // ---- fused radix-4 + untangle from natural planes:
        // X0(m) = v0+v1+v2+v3 ; X3(m) = (v0-v2) - i*(v1-v3).
        // zk = X0(k) = Z[k], zn = X3(512-k) = Z[2048-k].
        {
            float2 a0 = nat[qk0];
            float2 a1 = nat[(qk0 ^ 1) + 512];
            float2 a2 = nat[(qk0 ^ 2) + 1024];
            float2 a3 = nat[(qk0 ^ 3) + 1536];
            float2 zk = make_float2((a0.x + a1.x) + (a2.x + a3.x),
                                    (a0.y + a1.y) + (a2.y + a3.y));
            float2 b0 = nat[qn0];
            float2 b1 = nat[(qn0 ^ 1) + 512];
            float2 b2 = nat[(qn0 ^ 2) + 1024];
            float2 b3 = nat[(qn0 ^ 3) + 1536];
            float D0x = b0.x - b2.x, D0y = b0.y - b2.y;
            float D1x = b1.x - b3.x, D1y = b1.y - b3.y;
            float2 zn = make_float2(D0x - D1y, D0y + D1x);
            float Ex = 0.5f * (zk.x + zn.x);
            float Ey = 0.5f * (zk.y - zn.y);
            float Ox = 0.5f * (zk.y + zn.y);
            float Oy = -0.5f * (zk.x - zn.x);
            float xr = Ex + Ox * cs0 - Oy * sn0;
            float xi = Ey + Ox * sn0 + Oy * cs0;
            pw1 += xr * xr + xi * xi;
        }
        if (has2) {
            float2 a0 = nat[qk0 + 256];
            float2 a1 = nat[(qk0 ^ 1) + 768];
            float2 a2 = nat[(qk0 ^ 2) + 1280];
            float2 a3 = nat[(qk0 ^ 3) + 1792];
            float2 zk = make_float2((a0.x + a1.x) + (a2.x + a3.x),
                                    (a0.y + a1.y) + (a2.y + a3.y));
            float2 b0 = nat[qn0 - 256];
            float2 b1 = nat[(qn0 ^ 1) + 256];
            float2 b2 = nat[(qn0 ^ 2) + 768];
            float2 b3 = nat[(qn0 ^ 3) + 1280];
            float D0x = b0.x - b2.x, D0y = b0.y - b2.y;
            float D1x = b1.x - b3.x, D1y = b1.y - b3.y;
            float2 zn = make_float2(D0x - D1y, D0y + D1x);
            float Ex = 0.5f * (zk.x + zn.x);
            float Ey = 0.5f * (zk.y - zn.y);
            float Ox = 0.5f * (zk.y + zn.y);
            float Oy = -0.5f * (zk.x - zn.x);
            float xr = Ex + Ox * cs1 - Oy * sn1;
            float xi = Ey + Ox * sn1 + Oy * cs1;
            pw2 += xr * xr + xi * xi;
        }
        if (s + 1 < ns) __syncthreads();   // A-writes -> B-reads; untangle -> C(s+1)
    }

    // ---- single atomic flush per thread
    {
        float* accR = acc + (bid & (NREP - 1)) * ACC_ELEMS;
        int i0 = (sig * NROWS + (row - ROW0)) * ACC_STRIDE;
        atomicAdd(&accR[i0 + tid], pw1);
        if (has2) atomicAdd(&accR[i0 + 256 + tid], pw2);
    }
#undef LOADRAW
}

// Single block: out = sum over (row,k) of P_res/P_tgt, / 240.
// (dfreq=1, scale=480, mean(last 8)*16 => 2/480 = 1/240; /T cancels in ratio)
__global__ __launch_bounds__(256)
void reduce_kernel(const float* __restrict__ acc, float* __restrict__ out) {
    __shared__ float sh[256];
    int tid = threadIdx.x;
    float sum = 0.0f;
    for (int n = tid; n < NROWS * NFREQ; n += 256) {
        int r = n / NFREQ, k = n % NFREQ;
        float num = 0.0f, den = 0.0f;
        #pragma unroll
        for (int rep = 0; rep < NREP; ++rep) {
            num += acc[rep * ACC_ELEMS + r * ACC_STRIDE + k];
            den += acc[rep * ACC_ELEMS + (NROWS + r) * ACC_STRIDE + k];
        }
        sum += num / den;
    }
    sh[tid] = sum;
    __syncthreads();
    for (int s = 128; s > 0; s >>= 1) {
        if (tid < s) sh[tid] += sh[tid + s];
        __syncthreads();
    }
    if (tid == 0) out[0] = sh[0] * (1.0f / 240.0f);
}

extern "C" void kernel_launch(void* const* d_in, const int* in_sizes, int n_in,
                              void* d_out, int out_size, void* d_ws, size_t ws_size,
                              hipStream_t stream) {
    const float* pred = (const float*)d_in[0];
    const float* target = (const float*)d_in[1];
    float* acc = (float*)d_ws;   // NREP replicas of [2][NROWS][ACC_STRIDE] = 256 KiB

    hipMemsetAsync(acc, 0, NREP * ACC_ELEMS * sizeof(float), stream);
    psd_kernel<<<NBLOCKS, 256, 0, stream>>>(pred, target, acc);
    reduce_kernel<<<1, 256, 0, stream>>>(acc, (float*)d_out);
}